// Round 1
// baseline (683.331 us; speedup 1.0000x reference)
//
#include <hip/hip_runtime.h>
#include <hip/hip_bf16.h>
#include <math.h>

#define BB 8
#define DD 192
#define LLD 128
#define LLP 1024
#define FC1 1024
#define FC2 1024
#define FC3 512
#define NCLS 2

// y[b,l,e] = sum_d x[b,d,l]*W[e,d] + bias[e]
// x layout (B,D,L), y layout (B*L, D). grid = B*L blocks, block = D threads.
__global__ void att_proj_kernel(const float* __restrict__ x,
                                const float* __restrict__ W,
                                const float* __restrict__ bias,
                                float* __restrict__ y, int L) {
    int bl = blockIdx.x;
    int b = bl / L;
    int l = bl - b * L;
    int e = threadIdx.x;  // 0..D-1
    __shared__ float xs[DD];
    xs[e] = x[(b * DD + e) * L + l];
    __syncthreads();
    const float* Wr = W + e * DD;
    float a0 = bias[e], a1 = 0.f, a2 = 0.f, a3 = 0.f;
#pragma unroll 4
    for (int d = 0; d < DD; d += 4) {
        a0 = fmaf(xs[d + 0], Wr[d + 0], a0);
        a1 = fmaf(xs[d + 1], Wr[d + 1], a1);
        a2 = fmaf(xs[d + 2], Wr[d + 2], a2);
        a3 = fmaf(xs[d + 3], Wr[d + 3], a3);
    }
    y[bl * DD + e] = (a0 + a1) + (a2 + a3);
}

// Hd[b,l,d] = (1/LP) * sum_p relu(d_att[b,l,d] + p_att[b,p,d])
// grid = B*LD blocks, block = D threads.
__global__ void cross_mean_d_kernel(const float* __restrict__ da,
                                    const float* __restrict__ pa,
                                    float* __restrict__ Hd) {
    int bl = blockIdx.x;
    int b = bl / LLD;
    int d = threadIdx.x;
    float a = da[bl * DD + d];
    const float* pb = pa + (size_t)b * LLP * DD + d;
    float s0 = 0.f, s1 = 0.f, s2 = 0.f, s3 = 0.f;
    for (int p = 0; p < LLP; p += 4) {
        s0 += fmaxf(a + pb[(p + 0) * DD], 0.f);
        s1 += fmaxf(a + pb[(p + 1) * DD], 0.f);
        s2 += fmaxf(a + pb[(p + 2) * DD], 0.f);
        s3 += fmaxf(a + pb[(p + 3) * DD], 0.f);
    }
    Hd[bl * DD + d] = ((s0 + s1) + (s2 + s3)) * (1.0f / LLP);
}

// Hp[b,p,d] = (1/LD) * sum_l relu(d_att[b,l,d] + p_att[b,p,d])
// grid = B*LP blocks, block = D threads.
__global__ void cross_mean_p_kernel(const float* __restrict__ da,
                                    const float* __restrict__ pa,
                                    float* __restrict__ Hp) {
    int bp = blockIdx.x;
    int b = bp / LLP;
    int d = threadIdx.x;
    float a = pa[bp * DD + d];
    const float* db = da + (size_t)b * LLD * DD + d;
    float s0 = 0.f, s1 = 0.f, s2 = 0.f, s3 = 0.f;
    for (int l = 0; l < LLD; l += 4) {
        s0 += fmaxf(a + db[(l + 0) * DD], 0.f);
        s1 += fmaxf(a + db[(l + 1) * DD], 0.f);
        s2 += fmaxf(a + db[(l + 2) * DD], 0.f);
        s3 += fmaxf(a + db[(l + 3) * DD], 0.f);
    }
    Hp[bp * DD + d] = ((s0 + s1) + (s2 + s3)) * (1.0f / LLD);
}

// out[bl,e] = sigmoid( sum_d H[bl,d]*Wa[e,d] + ba[e] )
__global__ void att_gemm_sig_kernel(const float* __restrict__ H,
                                    const float* __restrict__ Wa,
                                    const float* __restrict__ ba,
                                    float* __restrict__ out) {
    int bl = blockIdx.x;
    int e = threadIdx.x;
    __shared__ float hs[DD];
    hs[e] = H[bl * DD + e];
    __syncthreads();
    const float* Wr = Wa + e * DD;
    float a0 = ba[e], a1 = 0.f, a2 = 0.f, a3 = 0.f;
#pragma unroll 4
    for (int d = 0; d < DD; d += 4) {
        a0 = fmaf(hs[d + 0], Wr[d + 0], a0);
        a1 = fmaf(hs[d + 1], Wr[d + 1], a1);
        a2 = fmaf(hs[d + 2], Wr[d + 2], a2);
        a3 = fmaf(hs[d + 3], Wr[d + 3], a3);
    }
    float acc = (a0 + a1) + (a2 + a3);
    out[bl * DD + e] = 1.0f / (1.0f + expf(-acc));
}

// pair[b, d]      = max_l drug[b,d,l] * (0.5 + catt[b,l,d])
// pair[b, D + d]  = max_p prot[b,d,p] * (0.5 + psig[b,p,d])
// grid = B blocks, block = D threads.
__global__ void pool_pair_kernel(const float* __restrict__ drug,
                                 const float* __restrict__ prot,
                                 const float* __restrict__ catt,
                                 const float* __restrict__ psig,
                                 float* __restrict__ pair) {
    int b = blockIdx.x;
    int d = threadIdx.x;
    const float* dr = drug + (size_t)(b * DD + d) * LLD;
    const float* ca = catt + (size_t)b * LLD * DD + d;
    float m = -INFINITY;
    for (int l = 0; l < LLD; ++l) {
        float v = dr[l] * (0.5f + ca[l * DD]);
        m = fmaxf(m, v);
    }
    pair[b * 2 * DD + d] = m;

    const float* pr = prot + (size_t)(b * DD + d) * LLP;
    const float* ps = psig + (size_t)b * LLP * DD + d;
    float m2 = -INFINITY;
    for (int p = 0; p < LLP; ++p) {
        float v = pr[p] * (0.5f + ps[p * DD]);
        m2 = fmaxf(m2, v);
    }
    pair[b * 2 * DD + DD + d] = m2;
}

// y[b,j] = act( sum_k x[b,k]*W[j,k] + bias[j] ), thread per (b,j)
__global__ void fc_kernel(const float* __restrict__ x,
                          const float* __restrict__ W,
                          const float* __restrict__ bias,
                          float* __restrict__ y,
                          int K, int N, int leaky) {
    int idx = blockIdx.x * blockDim.x + threadIdx.x;
    if (idx >= BB * N) return;
    int b = idx / N;
    int j = idx - b * N;
    const float* xr = x + b * K;
    const float* Wr = W + (size_t)j * K;
    float a0 = bias[j], a1 = 0.f, a2 = 0.f, a3 = 0.f;
    for (int k = 0; k < K; k += 4) {
        a0 = fmaf(xr[k + 0], Wr[k + 0], a0);
        a1 = fmaf(xr[k + 1], Wr[k + 1], a1);
        a2 = fmaf(xr[k + 2], Wr[k + 2], a2);
        a3 = fmaf(xr[k + 3], Wr[k + 3], a3);
    }
    float acc = (a0 + a1) + (a2 + a3);
    if (leaky) acc = (acc > 0.f) ? acc : 0.01f * acc;
    y[idx] = acc;
}

extern "C" void kernel_launch(void* const* d_in, const int* in_sizes, int n_in,
                              void* d_out, int out_size, void* d_ws, size_t ws_size,
                              hipStream_t stream) {
    const float* drug = (const float*)d_in[0];   // (B,D,LD)
    const float* prot = (const float*)d_in[1];   // (B,D,LP)
    const float* Wd = (const float*)d_in[2];
    const float* bd = (const float*)d_in[3];
    const float* Wp = (const float*)d_in[4];
    const float* bp = (const float*)d_in[5];
    const float* Wa = (const float*)d_in[6];
    const float* ba = (const float*)d_in[7];
    const float* W1 = (const float*)d_in[8];
    const float* b1 = (const float*)d_in[9];
    const float* W2 = (const float*)d_in[10];
    const float* b2 = (const float*)d_in[11];
    const float* W3 = (const float*)d_in[12];
    const float* b3 = (const float*)d_in[13];
    const float* Wo = (const float*)d_in[14];
    const float* bo = (const float*)d_in[15];
    float* out = (float*)d_out;

    float* ws = (float*)d_ws;
    const size_t n_datt = (size_t)BB * LLD * DD;   // 196608
    const size_t n_patt = (size_t)BB * LLP * DD;   // 1572864
    float* d_att = ws;                       // also reused for comp_att
    float* p_att = d_att + n_datt;           // also reused for prot_att(sig)
    float* Hd    = p_att + n_patt;
    float* Hp    = Hd + n_datt;
    float* pair  = Hp + n_patt;              // B*2D = 3072
    float* h1    = pair + (size_t)BB * 2 * DD;
    float* h2    = h1 + (size_t)BB * FC1;
    float* h3    = h2 + (size_t)BB * FC2;
    // total ~3.56M floats (~14.3 MB)

    // 1) projections
    att_proj_kernel<<<BB * LLD, DD, 0, stream>>>(drug, Wd, bd, d_att, LLD);
    att_proj_kernel<<<BB * LLP, DD, 0, stream>>>(prot, Wp, bp, p_att, LLP);

    // 2) cross means
    cross_mean_d_kernel<<<BB * LLD, DD, 0, stream>>>(d_att, p_att, Hd);
    cross_mean_p_kernel<<<BB * LLP, DD, 0, stream>>>(d_att, p_att, Hp);

    // 3) attention gemms + sigmoid (overwrite d_att/p_att buffers)
    float* catt = d_att;
    float* psig = p_att;
    att_gemm_sig_kernel<<<BB * LLD, DD, 0, stream>>>(Hd, Wa, ba, catt);
    att_gemm_sig_kernel<<<BB * LLP, DD, 0, stream>>>(Hp, Wa, ba, psig);

    // 4) gated residual + maxpool -> pair (B, 2D)
    pool_pair_kernel<<<BB, DD, 0, stream>>>(drug, prot, catt, psig, pair);

    // 5) MLP
    fc_kernel<<<(BB * FC1 + 255) / 256, 256, 0, stream>>>(pair, W1, b1, h1, 2 * DD, FC1, 1);
    fc_kernel<<<(BB * FC2 + 255) / 256, 256, 0, stream>>>(h1, W2, b2, h2, FC1, FC2, 1);
    fc_kernel<<<(BB * FC3 + 255) / 256, 256, 0, stream>>>(h2, W3, b3, h3, FC2, FC3, 1);
    fc_kernel<<<1, 64, 0, stream>>>(h3, Wo, bo, out, FC3, NCLS, 0);
}

// Round 2
// 399.332 us; speedup vs baseline: 1.7112x; 1.7112x over previous
//
#include <hip/hip_runtime.h>
#include <hip/hip_bf16.h>
#include <math.h>

#define BB 8
#define DD 192
#define LLD 128
#define LLP 1024
#define FC1 1024
#define FC2 1024
#define FC3 512
#define NCLS 2

// y[b,l,e] = sum_d x[b,d,l]*W[e,d] + bias[e]
// x layout (B,D,L), y layout (B*L, D). grid = B*L blocks, block = D threads.
__global__ void att_proj_kernel(const float* __restrict__ x,
                                const float* __restrict__ W,
                                const float* __restrict__ bias,
                                float* __restrict__ y, int L) {
    int bl = blockIdx.x;
    int b = bl / L;
    int l = bl - b * L;
    int e = threadIdx.x;  // 0..D-1
    __shared__ float xs[DD];
    xs[e] = x[(b * DD + e) * L + l];
    __syncthreads();
    const float* Wr = W + e * DD;
    float a0 = bias[e], a1 = 0.f, a2 = 0.f, a3 = 0.f;
#pragma unroll 4
    for (int d = 0; d < DD; d += 4) {
        a0 = fmaf(xs[d + 0], Wr[d + 0], a0);
        a1 = fmaf(xs[d + 1], Wr[d + 1], a1);
        a2 = fmaf(xs[d + 2], Wr[d + 2], a2);
        a3 = fmaf(xs[d + 3], Wr[d + 3], a3);
    }
    y[bl * DD + e] = (a0 + a1) + (a2 + a3);
}

// Hd[b,l,d] = (1/LP) * sum_p relu(d_att[b,l,d] + p_att[b,p,d])
// grid = B*LD blocks, block = D threads.
__global__ void cross_mean_d_kernel(const float* __restrict__ da,
                                    const float* __restrict__ pa,
                                    float* __restrict__ Hd) {
    int bl = blockIdx.x;
    int b = bl / LLD;
    int d = threadIdx.x;
    float a = da[bl * DD + d];
    const float* pb = pa + (size_t)b * LLP * DD + d;
    float s0 = 0.f, s1 = 0.f, s2 = 0.f, s3 = 0.f;
    float s4 = 0.f, s5 = 0.f, s6 = 0.f, s7 = 0.f;
    for (int p = 0; p < LLP; p += 8) {
        s0 += fmaxf(a + pb[(p + 0) * DD], 0.f);
        s1 += fmaxf(a + pb[(p + 1) * DD], 0.f);
        s2 += fmaxf(a + pb[(p + 2) * DD], 0.f);
        s3 += fmaxf(a + pb[(p + 3) * DD], 0.f);
        s4 += fmaxf(a + pb[(p + 4) * DD], 0.f);
        s5 += fmaxf(a + pb[(p + 5) * DD], 0.f);
        s6 += fmaxf(a + pb[(p + 6) * DD], 0.f);
        s7 += fmaxf(a + pb[(p + 7) * DD], 0.f);
    }
    Hd[bl * DD + d] = (((s0 + s1) + (s2 + s3)) + ((s4 + s5) + (s6 + s7))) * (1.0f / LLP);
}

// Hp[b,p,d] = (1/LD) * sum_l relu(d_att[b,l,d] + p_att[b,p,d])
// grid = B*LP blocks, block = D threads.
__global__ void cross_mean_p_kernel(const float* __restrict__ da,
                                    const float* __restrict__ pa,
                                    float* __restrict__ Hp) {
    int bp = blockIdx.x;
    int b = bp / LLP;
    int d = threadIdx.x;
    float a = pa[bp * DD + d];
    const float* db = da + (size_t)b * LLD * DD + d;
    float s0 = 0.f, s1 = 0.f, s2 = 0.f, s3 = 0.f;
    float s4 = 0.f, s5 = 0.f, s6 = 0.f, s7 = 0.f;
    for (int l = 0; l < LLD; l += 8) {
        s0 += fmaxf(a + db[(l + 0) * DD], 0.f);
        s1 += fmaxf(a + db[(l + 1) * DD], 0.f);
        s2 += fmaxf(a + db[(l + 2) * DD], 0.f);
        s3 += fmaxf(a + db[(l + 3) * DD], 0.f);
        s4 += fmaxf(a + db[(l + 4) * DD], 0.f);
        s5 += fmaxf(a + db[(l + 5) * DD], 0.f);
        s6 += fmaxf(a + db[(l + 6) * DD], 0.f);
        s7 += fmaxf(a + db[(l + 7) * DD], 0.f);
    }
    Hp[bp * DD + d] = (((s0 + s1) + (s2 + s3)) + ((s4 + s5) + (s6 + s7))) * (1.0f / LLD);
}

// out_t[(b*D+e)*L + l] = sigmoid( sum_d H[bl,d]*Wa[e,d] + ba[e] )
// Writes TRANSPOSED (B,D,L) layout so the pool kernel reads coalesced.
__global__ void att_gemm_sig_kernel(const float* __restrict__ H,
                                    const float* __restrict__ Wa,
                                    const float* __restrict__ ba,
                                    float* __restrict__ out_t, int L) {
    int bl = blockIdx.x;
    int b = bl / L;
    int l = bl - b * L;
    int e = threadIdx.x;
    __shared__ float hs[DD];
    hs[e] = H[bl * DD + e];
    __syncthreads();
    const float* Wr = Wa + e * DD;
    float a0 = ba[e], a1 = 0.f, a2 = 0.f, a3 = 0.f;
#pragma unroll 4
    for (int d = 0; d < DD; d += 4) {
        a0 = fmaf(hs[d + 0], Wr[d + 0], a0);
        a1 = fmaf(hs[d + 1], Wr[d + 1], a1);
        a2 = fmaf(hs[d + 2], Wr[d + 2], a2);
        a3 = fmaf(hs[d + 3], Wr[d + 3], a3);
    }
    float acc = (a0 + a1) + (a2 + a3);
    out_t[((size_t)b * DD + e) * L + l] = 1.0f / (1.0f + expf(-acc));
}

// One wave per (b,d). Coalesced contiguous reads; shfl butterfly max-reduce.
// pair[b, d]     = max_l drug[b,d,l] * (0.5 + catt_t[b,d,l])
// pair[b, D + d] = max_p prot[b,d,p] * (0.5 + psig_t[b,d,p])
// grid = B*D blocks of 64 threads.
__global__ void pool_pair_kernel(const float* __restrict__ drug,
                                 const float* __restrict__ prot,
                                 const float* __restrict__ catt_t,
                                 const float* __restrict__ psig_t,
                                 float* __restrict__ pair) {
    int bd = blockIdx.x;           // b*DD + d
    int b = bd / DD;
    int d = bd - b * DD;
    int lane = threadIdx.x;        // 0..63

    const float* dr = drug + (size_t)bd * LLD;
    const float* ca = catt_t + (size_t)bd * LLD;
    float m1 = -INFINITY;
#pragma unroll
    for (int k = 0; k < LLD / 64; ++k) {
        int l = lane + 64 * k;
        m1 = fmaxf(m1, dr[l] * (0.5f + ca[l]));
    }

    const float* pr = prot + (size_t)bd * LLP;
    const float* ps = psig_t + (size_t)bd * LLP;
    float m2 = -INFINITY;
#pragma unroll
    for (int k = 0; k < LLP / 64; ++k) {
        int p = lane + 64 * k;
        m2 = fmaxf(m2, pr[p] * (0.5f + ps[p]));
    }

#pragma unroll
    for (int off = 32; off > 0; off >>= 1) {
        m1 = fmaxf(m1, __shfl_xor(m1, off));
        m2 = fmaxf(m2, __shfl_xor(m2, off));
    }
    if (lane == 0) {
        pair[b * 2 * DD + d] = m1;
        pair[b * 2 * DD + DD + d] = m2;
    }
}

// One 64-lane wave per output (b,j). Lanes split K (coalesced W reads).
__global__ void fc_wave_kernel(const float* __restrict__ x,
                               const float* __restrict__ W,
                               const float* __restrict__ bias,
                               float* __restrict__ y,
                               int K, int N, int leaky) {
    int gtid = blockIdx.x * blockDim.x + threadIdx.x;
    int wid = gtid >> 6;
    int lane = gtid & 63;
    if (wid >= BB * N) return;
    int b = wid / N;
    int j = wid - b * N;
    const float* xr = x + (size_t)b * K;
    const float* Wr = W + (size_t)j * K;
    float s = 0.f;
    for (int k = lane; k < K; k += 64) s = fmaf(xr[k], Wr[k], s);
#pragma unroll
    for (int off = 32; off > 0; off >>= 1) s += __shfl_xor(s, off);
    if (lane == 0) {
        float acc = s + bias[j];
        if (leaky) acc = (acc > 0.f) ? acc : 0.01f * acc;
        y[wid] = acc;
    }
}

extern "C" void kernel_launch(void* const* d_in, const int* in_sizes, int n_in,
                              void* d_out, int out_size, void* d_ws, size_t ws_size,
                              hipStream_t stream) {
    const float* drug = (const float*)d_in[0];   // (B,D,LD)
    const float* prot = (const float*)d_in[1];   // (B,D,LP)
    const float* Wd = (const float*)d_in[2];
    const float* bd = (const float*)d_in[3];
    const float* Wp = (const float*)d_in[4];
    const float* bp = (const float*)d_in[5];
    const float* Wa = (const float*)d_in[6];
    const float* ba = (const float*)d_in[7];
    const float* W1 = (const float*)d_in[8];
    const float* b1 = (const float*)d_in[9];
    const float* W2 = (const float*)d_in[10];
    const float* b2 = (const float*)d_in[11];
    const float* W3 = (const float*)d_in[12];
    const float* b3 = (const float*)d_in[13];
    const float* Wo = (const float*)d_in[14];
    const float* bo = (const float*)d_in[15];
    float* out = (float*)d_out;

    float* ws = (float*)d_ws;
    const size_t n_datt = (size_t)BB * LLD * DD;   // 196608
    const size_t n_patt = (size_t)BB * LLP * DD;   // 1572864
    float* d_att = ws;                       // reused for catt_t (B,D,LD)
    float* p_att = d_att + n_datt;           // reused for psig_t (B,D,LP)
    float* Hd    = p_att + n_patt;
    float* Hp    = Hd + n_datt;
    float* pair  = Hp + n_patt;              // B*2D = 3072
    float* h1    = pair + (size_t)BB * 2 * DD;
    float* h2    = h1 + (size_t)BB * FC1;
    float* h3    = h2 + (size_t)BB * FC2;

    // 1) projections
    att_proj_kernel<<<BB * LLD, DD, 0, stream>>>(drug, Wd, bd, d_att, LLD);
    att_proj_kernel<<<BB * LLP, DD, 0, stream>>>(prot, Wp, bp, p_att, LLP);

    // 2) cross means
    cross_mean_d_kernel<<<BB * LLD, DD, 0, stream>>>(d_att, p_att, Hd);
    cross_mean_p_kernel<<<BB * LLP, DD, 0, stream>>>(d_att, p_att, Hp);

    // 3) attention gemms + sigmoid, writing transposed (B,D,L) layouts
    //    (overwrite d_att/p_att buffers — same sizes)
    float* catt_t = d_att;
    float* psig_t = p_att;
    att_gemm_sig_kernel<<<BB * LLD, DD, 0, stream>>>(Hd, Wa, ba, catt_t, LLD);
    att_gemm_sig_kernel<<<BB * LLP, DD, 0, stream>>>(Hp, Wa, ba, psig_t, LLP);

    // 4) gated residual + maxpool -> pair (B, 2D); wave per (b,d)
    pool_pair_kernel<<<BB * DD, 64, 0, stream>>>(drug, prot, catt_t, psig_t, pair);

    // 5) MLP — wave per output element
    fc_wave_kernel<<<(BB * FC1 * 64) / 256, 256, 0, stream>>>(pair, W1, b1, h1, 2 * DD, FC1, 1);
    fc_wave_kernel<<<(BB * FC2 * 64) / 256, 256, 0, stream>>>(h1, W2, b2, h2, FC1, FC2, 1);
    fc_wave_kernel<<<(BB * FC3 * 64) / 256, 256, 0, stream>>>(h2, W3, b3, h3, FC2, FC3, 1);
    fc_wave_kernel<<<(BB * NCLS * 64 + 255) / 256, 256, 0, stream>>>(h3, Wo, bo, out, FC3, NCLS, 0);
}

// Round 3
// 295.693 us; speedup vs baseline: 2.3110x; 1.3505x over previous
//
#include <hip/hip_runtime.h>
#include <hip/hip_bf16.h>
#include <math.h>

#define BB 8
#define DD 192
#define LLD 128
#define LLP 1024
#define FC1 1024
#define FC2 1024
#define FC3 512
#define NCLS 2
#define LT 16   // l-tile for the sigmoid-GEMM

// y[b,l,e] = sum_d x[b,d,l]*W[e,d] + bias[e]
// x layout (B,D,L), y layout (B*L, D). grid = B*L blocks, block = D threads.
__global__ void att_proj_kernel(const float* __restrict__ x,
                                const float* __restrict__ W,
                                const float* __restrict__ bias,
                                float* __restrict__ y, int L) {
    int bl = blockIdx.x;
    int b = bl / L;
    int l = bl - b * L;
    int e = threadIdx.x;  // 0..D-1
    __shared__ float xs[DD];
    xs[e] = x[(b * DD + e) * L + l];
    __syncthreads();
    const float* Wr = W + e * DD;
    float a0 = bias[e], a1 = 0.f, a2 = 0.f, a3 = 0.f;
#pragma unroll 4
    for (int d = 0; d < DD; d += 4) {
        a0 = fmaf(xs[d + 0], Wr[d + 0], a0);
        a1 = fmaf(xs[d + 1], Wr[d + 1], a1);
        a2 = fmaf(xs[d + 2], Wr[d + 2], a2);
        a3 = fmaf(xs[d + 3], Wr[d + 3], a3);
    }
    y[bl * DD + e] = (a0 + a1) + (a2 + a3);
}

// Hd[b,l,d] = (1/LP) * sum_p relu(d_att[b,l,d] + p_att[b,p,d])
__global__ void cross_mean_d_kernel(const float* __restrict__ da,
                                    const float* __restrict__ pa,
                                    float* __restrict__ Hd) {
    int bl = blockIdx.x;
    int b = bl / LLD;
    int d = threadIdx.x;
    float a = da[bl * DD + d];
    const float* pb = pa + (size_t)b * LLP * DD + d;
    float s0 = 0.f, s1 = 0.f, s2 = 0.f, s3 = 0.f;
    float s4 = 0.f, s5 = 0.f, s6 = 0.f, s7 = 0.f;
    for (int p = 0; p < LLP; p += 8) {
        s0 += fmaxf(a + pb[(p + 0) * DD], 0.f);
        s1 += fmaxf(a + pb[(p + 1) * DD], 0.f);
        s2 += fmaxf(a + pb[(p + 2) * DD], 0.f);
        s3 += fmaxf(a + pb[(p + 3) * DD], 0.f);
        s4 += fmaxf(a + pb[(p + 4) * DD], 0.f);
        s5 += fmaxf(a + pb[(p + 5) * DD], 0.f);
        s6 += fmaxf(a + pb[(p + 6) * DD], 0.f);
        s7 += fmaxf(a + pb[(p + 7) * DD], 0.f);
    }
    Hd[bl * DD + d] = (((s0 + s1) + (s2 + s3)) + ((s4 + s5) + (s6 + s7))) * (1.0f / LLP);
}

// Hp[b,p,d] = (1/LD) * sum_l relu(d_att[b,l,d] + p_att[b,p,d])
__global__ void cross_mean_p_kernel(const float* __restrict__ da,
                                    const float* __restrict__ pa,
                                    float* __restrict__ Hp) {
    int bp = blockIdx.x;
    int b = bp / LLP;
    int d = threadIdx.x;
    float a = pa[bp * DD + d];
    const float* db = da + (size_t)b * LLD * DD + d;
    float s0 = 0.f, s1 = 0.f, s2 = 0.f, s3 = 0.f;
    float s4 = 0.f, s5 = 0.f, s6 = 0.f, s7 = 0.f;
    for (int l = 0; l < LLD; l += 8) {
        s0 += fmaxf(a + db[(l + 0) * DD], 0.f);
        s1 += fmaxf(a + db[(l + 1) * DD], 0.f);
        s2 += fmaxf(a + db[(l + 2) * DD], 0.f);
        s3 += fmaxf(a + db[(l + 3) * DD], 0.f);
        s4 += fmaxf(a + db[(l + 4) * DD], 0.f);
        s5 += fmaxf(a + db[(l + 5) * DD], 0.f);
        s6 += fmaxf(a + db[(l + 6) * DD], 0.f);
        s7 += fmaxf(a + db[(l + 7) * DD], 0.f);
    }
    Hp[bp * DD + d] = (((s0 + s1) + (s2 + s3)) + ((s4 + s5) + (s6 + s7))) * (1.0f / LLD);
}

// Tiled sigmoid-GEMM with transposed, fully-coalesced output.
// For each (b, l-tile of LT): C[j][e] = sigmoid(H[b,l0+j,:]·Wa[e,:] + ba[e])
// written to out_t[(b*D+e)*L + l0 + j]  (layout (B,D,L)).
// grid = B * (L/LT) blocks, block = D threads (thread = e).
__global__ void att_gemm_sig_tiled(const float* __restrict__ H,
                                   const float* __restrict__ Wa,
                                   const float* __restrict__ ba,
                                   float* __restrict__ out_t, int L) {
    int ntiles = L / LT;
    int blk = blockIdx.x;
    int b = blk / ntiles;
    int l0 = (blk - b * ntiles) * LT;
    int tid = threadIdx.x;  // 0..191

    __shared__ float hs[LT][DD];       // H tile, float4-friendly stride
    __shared__ float cs[LT][DD + 1];   // result tile, +1 pad for transpose read

    const float* Hbase = H + ((size_t)b * L + l0) * DD;
#pragma unroll
    for (int j = 0; j < LT; ++j)
        hs[j][tid] = Hbase[j * DD + tid];          // coalesced
    __syncthreads();

    const int e = tid;
    const float bias = ba[e];
    float acc[LT];
#pragma unroll
    for (int j = 0; j < LT; ++j) acc[j] = bias;

    const float4* Wr4 = (const float4*)(Wa + (size_t)e * DD);
#pragma unroll 2
    for (int d4 = 0; d4 < DD / 4; ++d4) {
        float4 w = Wr4[d4];
#pragma unroll
        for (int j = 0; j < LT; ++j) {
            float4 h = *(const float4*)&hs[j][d4 * 4];  // broadcast read
            acc[j] = fmaf(h.x, w.x, acc[j]);
            acc[j] = fmaf(h.y, w.y, acc[j]);
            acc[j] = fmaf(h.z, w.z, acc[j]);
            acc[j] = fmaf(h.w, w.w, acc[j]);
        }
    }

#pragma unroll
    for (int j = 0; j < LT; ++j)
        cs[j][e] = 1.0f / (1.0f + __expf(-acc[j]));
    __syncthreads();

    // write-out: lanes cover l (fast index) -> coalesced 64B segments
    float* obase = out_t + (size_t)b * DD * L + l0;
    for (int idx = tid; idx < LT * DD; idx += DD) {
        int eo = idx >> 4;   // idx / LT
        int j = idx & (LT - 1);
        obase[(size_t)eo * L + j] = cs[j][eo];
    }
}

// One wave per (b,d). Coalesced contiguous reads; shfl butterfly max-reduce.
__global__ void pool_pair_kernel(const float* __restrict__ drug,
                                 const float* __restrict__ prot,
                                 const float* __restrict__ catt_t,
                                 const float* __restrict__ psig_t,
                                 float* __restrict__ pair) {
    int bd = blockIdx.x;           // b*DD + d
    int b = bd / DD;
    int d = bd - b * DD;
    int lane = threadIdx.x;        // 0..63

    const float* dr = drug + (size_t)bd * LLD;
    const float* ca = catt_t + (size_t)bd * LLD;
    float m1 = -INFINITY;
#pragma unroll
    for (int k = 0; k < LLD / 64; ++k) {
        int l = lane + 64 * k;
        m1 = fmaxf(m1, dr[l] * (0.5f + ca[l]));
    }

    const float* pr = prot + (size_t)bd * LLP;
    const float* ps = psig_t + (size_t)bd * LLP;
    float m2 = -INFINITY;
#pragma unroll
    for (int k = 0; k < LLP / 64; ++k) {
        int p = lane + 64 * k;
        m2 = fmaxf(m2, pr[p] * (0.5f + ps[p]));
    }

#pragma unroll
    for (int off = 32; off > 0; off >>= 1) {
        m1 = fmaxf(m1, __shfl_xor(m1, off));
        m2 = fmaxf(m2, __shfl_xor(m2, off));
    }
    if (lane == 0) {
        pair[b * 2 * DD + d] = m1;
        pair[b * 2 * DD + DD + d] = m2;
    }
}

// One 64-lane wave per output (b,j). Lanes split K (coalesced W reads).
__global__ void fc_wave_kernel(const float* __restrict__ x,
                               const float* __restrict__ W,
                               const float* __restrict__ bias,
                               float* __restrict__ y,
                               int K, int N, int leaky) {
    int gtid = blockIdx.x * blockDim.x + threadIdx.x;
    int wid = gtid >> 6;
    int lane = gtid & 63;
    if (wid >= BB * N) return;
    int b = wid / N;
    int j = wid - b * N;
    const float* xr = x + (size_t)b * K;
    const float* Wr = W + (size_t)j * K;
    float s = 0.f;
    for (int k = lane; k < K; k += 64) s = fmaf(xr[k], Wr[k], s);
#pragma unroll
    for (int off = 32; off > 0; off >>= 1) s += __shfl_xor(s, off);
    if (lane == 0) {
        float acc = s + bias[j];
        if (leaky) acc = (acc > 0.f) ? acc : 0.01f * acc;
        y[wid] = acc;
    }
}

extern "C" void kernel_launch(void* const* d_in, const int* in_sizes, int n_in,
                              void* d_out, int out_size, void* d_ws, size_t ws_size,
                              hipStream_t stream) {
    const float* drug = (const float*)d_in[0];   // (B,D,LD)
    const float* prot = (const float*)d_in[1];   // (B,D,LP)
    const float* Wd = (const float*)d_in[2];
    const float* bd = (const float*)d_in[3];
    const float* Wp = (const float*)d_in[4];
    const float* bp = (const float*)d_in[5];
    const float* Wa = (const float*)d_in[6];
    const float* ba = (const float*)d_in[7];
    const float* W1 = (const float*)d_in[8];
    const float* b1 = (const float*)d_in[9];
    const float* W2 = (const float*)d_in[10];
    const float* b2 = (const float*)d_in[11];
    const float* W3 = (const float*)d_in[12];
    const float* b3 = (const float*)d_in[13];
    const float* Wo = (const float*)d_in[14];
    const float* bo = (const float*)d_in[15];
    float* out = (float*)d_out;

    float* ws = (float*)d_ws;
    const size_t n_datt = (size_t)BB * LLD * DD;   // 196608
    const size_t n_patt = (size_t)BB * LLP * DD;   // 1572864
    float* d_att = ws;                       // reused for catt_t (B,D,LD)
    float* p_att = d_att + n_datt;           // reused for psig_t (B,D,LP)
    float* Hd    = p_att + n_patt;
    float* Hp    = Hd + n_datt;
    float* pair  = Hp + n_patt;              // B*2D = 3072
    float* h1    = pair + (size_t)BB * 2 * DD;
    float* h2    = h1 + (size_t)BB * FC1;
    float* h3    = h2 + (size_t)BB * FC2;

    // 1) projections
    att_proj_kernel<<<BB * LLD, DD, 0, stream>>>(drug, Wd, bd, d_att, LLD);
    att_proj_kernel<<<BB * LLP, DD, 0, stream>>>(prot, Wp, bp, p_att, LLP);

    // 2) cross means
    cross_mean_d_kernel<<<BB * LLD, DD, 0, stream>>>(d_att, p_att, Hd);
    cross_mean_p_kernel<<<BB * LLP, DD, 0, stream>>>(d_att, p_att, Hp);

    // 3) attention gemms + sigmoid, writing transposed (B,D,L) layouts
    //    via LDS-staged coalesced stores (overwrite d_att/p_att buffers)
    float* catt_t = d_att;
    float* psig_t = p_att;
    att_gemm_sig_tiled<<<BB * (LLD / LT), DD, 0, stream>>>(Hd, Wa, ba, catt_t, LLD);
    att_gemm_sig_tiled<<<BB * (LLP / LT), DD, 0, stream>>>(Hp, Wa, ba, psig_t, LLP);

    // 4) gated residual + maxpool -> pair (B, 2D); wave per (b,d)
    pool_pair_kernel<<<BB * DD, 64, 0, stream>>>(drug, prot, catt_t, psig_t, pair);

    // 5) MLP — wave per output element
    fc_wave_kernel<<<(BB * FC1 * 64) / 256, 256, 0, stream>>>(pair, W1, b1, h1, 2 * DD, FC1, 1);
    fc_wave_kernel<<<(BB * FC2 * 64) / 256, 256, 0, stream>>>(h1, W2, b2, h2, FC1, FC2, 1);
    fc_wave_kernel<<<(BB * FC3 * 64) / 256, 256, 0, stream>>>(h2, W3, b3, h3, FC2, FC3, 1);
    fc_wave_kernel<<<(BB * NCLS * 64 + 255) / 256, 256, 0, stream>>>(h3, Wo, bo, out, FC3, NCLS, 0);
}

// Round 4
// 190.490 us; speedup vs baseline: 3.5872x; 1.5523x over previous
//
#include <hip/hip_runtime.h>
#include <hip/hip_bf16.h>
#include <math.h>

#define BB 8
#define DD 192
#define LLD 128
#define LLP 1024
#define FC1 1024
#define FC2 1024
#define FC3 512
#define NCLS 2
#define LT 16   // l-tile for the tiled GEMM kernels

// Tiled projection: y[b*L + l, e] = sum_d x[b,d,l]*W[e,d] + bias[e]
// x layout (B,D,L). grid = B*(L/LT) blocks, block = D threads (thread = e).
// x-slab staged in LDS (coalesced 64B segments); W read as per-lane float4,
// amortized over LT outputs; output rows contiguous (coalesced).
__global__ void att_proj_tiled(const float* __restrict__ x,
                               const float* __restrict__ W,
                               const float* __restrict__ bias,
                               float* __restrict__ y, int L) {
    int ntiles = L / LT;
    int blk = blockIdx.x;
    int b = blk / ntiles;
    int l0 = (blk - b * ntiles) * LT;
    int tid = threadIdx.x;  // 0..191

    __shared__ float xs[LT][DD + 4];   // xs[j][d] = x[b,d,l0+j]; stride 196 (16B-aligned)

    const float* xbase = x + (size_t)b * DD * L + l0;
#pragma unroll
    for (int k = 0; k < LT; ++k) {
        int idx = tid + k * DD;        // covers DD*LT = 3072
        int d = idx >> 4;              // idx / 16
        int j = idx & (LT - 1);
        xs[j][d] = xbase[(size_t)d * L + j];
    }
    __syncthreads();

    const int e = tid;
    const float be = bias[e];
    float acc[LT];
#pragma unroll
    for (int j = 0; j < LT; ++j) acc[j] = be;

    const float4* Wr4 = (const float4*)(W + (size_t)e * DD);
#pragma unroll 2
    for (int d4 = 0; d4 < DD / 4; ++d4) {
        float4 w = Wr4[d4];
#pragma unroll
        for (int j = 0; j < LT; ++j) {
            float4 h = *(const float4*)&xs[j][d4 * 4];
            acc[j] = fmaf(h.x, w.x, acc[j]);
            acc[j] = fmaf(h.y, w.y, acc[j]);
            acc[j] = fmaf(h.z, w.z, acc[j]);
            acc[j] = fmaf(h.w, w.w, acc[j]);
        }
    }

    float* ybase = y + ((size_t)b * L + l0) * DD;
#pragma unroll
    for (int j = 0; j < LT; ++j)
        ybase[(size_t)j * DD + e] = acc[j];
}

// Hd[b,l,d] = (1/LP) * sum_p relu(d_att[b,l,d] + p_att[b,p,d])
__global__ void cross_mean_d_kernel(const float* __restrict__ da,
                                    const float* __restrict__ pa,
                                    float* __restrict__ Hd) {
    int bl = blockIdx.x;
    int b = bl / LLD;
    int d = threadIdx.x;
    float a = da[bl * DD + d];
    const float* pb = pa + (size_t)b * LLP * DD + d;
    float s0 = 0.f, s1 = 0.f, s2 = 0.f, s3 = 0.f;
    float s4 = 0.f, s5 = 0.f, s6 = 0.f, s7 = 0.f;
    for (int p = 0; p < LLP; p += 8) {
        s0 += fmaxf(a + pb[(p + 0) * DD], 0.f);
        s1 += fmaxf(a + pb[(p + 1) * DD], 0.f);
        s2 += fmaxf(a + pb[(p + 2) * DD], 0.f);
        s3 += fmaxf(a + pb[(p + 3) * DD], 0.f);
        s4 += fmaxf(a + pb[(p + 4) * DD], 0.f);
        s5 += fmaxf(a + pb[(p + 5) * DD], 0.f);
        s6 += fmaxf(a + pb[(p + 6) * DD], 0.f);
        s7 += fmaxf(a + pb[(p + 7) * DD], 0.f);
    }
    Hd[bl * DD + d] = (((s0 + s1) + (s2 + s3)) + ((s4 + s5) + (s6 + s7))) * (1.0f / LLP);
}

// Hp[b,p,d] = (1/LD) * sum_l relu(d_att[b,l,d] + p_att[b,p,d])
__global__ void cross_mean_p_kernel(const float* __restrict__ da,
                                    const float* __restrict__ pa,
                                    float* __restrict__ Hp) {
    int bp = blockIdx.x;
    int b = bp / LLP;
    int d = threadIdx.x;
    float a = pa[bp * DD + d];
    const float* db = da + (size_t)b * LLD * DD + d;
    float s0 = 0.f, s1 = 0.f, s2 = 0.f, s3 = 0.f;
    float s4 = 0.f, s5 = 0.f, s6 = 0.f, s7 = 0.f;
    for (int l = 0; l < LLD; l += 8) {
        s0 += fmaxf(a + db[(l + 0) * DD], 0.f);
        s1 += fmaxf(a + db[(l + 1) * DD], 0.f);
        s2 += fmaxf(a + db[(l + 2) * DD], 0.f);
        s3 += fmaxf(a + db[(l + 3) * DD], 0.f);
        s4 += fmaxf(a + db[(l + 4) * DD], 0.f);
        s5 += fmaxf(a + db[(l + 5) * DD], 0.f);
        s6 += fmaxf(a + db[(l + 6) * DD], 0.f);
        s7 += fmaxf(a + db[(l + 7) * DD], 0.f);
    }
    Hp[bp * DD + d] = (((s0 + s1) + (s2 + s3)) + ((s4 + s5) + (s6 + s7))) * (1.0f / LLD);
}

// Tiled sigmoid-GEMM with transposed, fully-coalesced output.
// For each (b, l-tile of LT): C[j][e] = sigmoid(H[b,l0+j,:]·Wa[e,:] + ba[e])
// written to out_t[(b*D+e)*L + l0 + j]  (layout (B,D,L)).
__global__ void att_gemm_sig_tiled(const float* __restrict__ H,
                                   const float* __restrict__ Wa,
                                   const float* __restrict__ ba,
                                   float* __restrict__ out_t, int L) {
    int ntiles = L / LT;
    int blk = blockIdx.x;
    int b = blk / ntiles;
    int l0 = (blk - b * ntiles) * LT;
    int tid = threadIdx.x;  // 0..191

    __shared__ float hs[LT][DD];       // H tile
    __shared__ float cs[LT][DD + 1];   // result tile, +1 pad for transpose read

    const float* Hbase = H + ((size_t)b * L + l0) * DD;
#pragma unroll
    for (int j = 0; j < LT; ++j)
        hs[j][tid] = Hbase[j * DD + tid];          // coalesced
    __syncthreads();

    const int e = tid;
    const float bias = ba[e];
    float acc[LT];
#pragma unroll
    for (int j = 0; j < LT; ++j) acc[j] = bias;

    const float4* Wr4 = (const float4*)(Wa + (size_t)e * DD);
#pragma unroll 2
    for (int d4 = 0; d4 < DD / 4; ++d4) {
        float4 w = Wr4[d4];
#pragma unroll
        for (int j = 0; j < LT; ++j) {
            float4 h = *(const float4*)&hs[j][d4 * 4];  // broadcast read
            acc[j] = fmaf(h.x, w.x, acc[j]);
            acc[j] = fmaf(h.y, w.y, acc[j]);
            acc[j] = fmaf(h.z, w.z, acc[j]);
            acc[j] = fmaf(h.w, w.w, acc[j]);
        }
    }

#pragma unroll
    for (int j = 0; j < LT; ++j)
        cs[j][e] = 1.0f / (1.0f + __expf(-acc[j]));
    __syncthreads();

    // write-out: lanes cover l (fast index) -> coalesced segments
    float* obase = out_t + (size_t)b * DD * L + l0;
    for (int idx = tid; idx < LT * DD; idx += DD) {
        int eo = idx >> 4;   // idx / LT
        int j = idx & (LT - 1);
        obase[(size_t)eo * L + j] = cs[j][eo];
    }
}

// One wave per (b,d). Coalesced contiguous reads; shfl butterfly max-reduce.
__global__ void pool_pair_kernel(const float* __restrict__ drug,
                                 const float* __restrict__ prot,
                                 const float* __restrict__ catt_t,
                                 const float* __restrict__ psig_t,
                                 float* __restrict__ pair) {
    int bd = blockIdx.x;           // b*DD + d
    int b = bd / DD;
    int d = bd - b * DD;
    int lane = threadIdx.x;        // 0..63

    const float* dr = drug + (size_t)bd * LLD;
    const float* ca = catt_t + (size_t)bd * LLD;
    float m1 = -INFINITY;
#pragma unroll
    for (int k = 0; k < LLD / 64; ++k) {
        int l = lane + 64 * k;
        m1 = fmaxf(m1, dr[l] * (0.5f + ca[l]));
    }

    const float* pr = prot + (size_t)bd * LLP;
    const float* ps = psig_t + (size_t)bd * LLP;
    float m2 = -INFINITY;
#pragma unroll
    for (int k = 0; k < LLP / 64; ++k) {
        int p = lane + 64 * k;
        m2 = fmaxf(m2, pr[p] * (0.5f + ps[p]));
    }

#pragma unroll
    for (int off = 32; off > 0; off >>= 1) {
        m1 = fmaxf(m1, __shfl_xor(m1, off));
        m2 = fmaxf(m2, __shfl_xor(m2, off));
    }
    if (lane == 0) {
        pair[b * 2 * DD + d] = m1;
        pair[b * 2 * DD + DD + d] = m2;
    }
}

// One 64-lane wave per output (b,j). Lanes split K (coalesced W reads).
__global__ void fc_wave_kernel(const float* __restrict__ x,
                               const float* __restrict__ W,
                               const float* __restrict__ bias,
                               float* __restrict__ y,
                               int K, int N, int leaky) {
    int gtid = blockIdx.x * blockDim.x + threadIdx.x;
    int wid = gtid >> 6;
    int lane = gtid & 63;
    if (wid >= BB * N) return;
    int b = wid / N;
    int j = wid - b * N;
    const float* xr = x + (size_t)b * K;
    const float* Wr = W + (size_t)j * K;
    float s = 0.f;
    for (int k = lane; k < K; k += 64) s = fmaf(xr[k], Wr[k], s);
#pragma unroll
    for (int off = 32; off > 0; off >>= 1) s += __shfl_xor(s, off);
    if (lane == 0) {
        float acc = s + bias[j];
        if (leaky) acc = (acc > 0.f) ? acc : 0.01f * acc;
        y[wid] = acc;
    }
}

extern "C" void kernel_launch(void* const* d_in, const int* in_sizes, int n_in,
                              void* d_out, int out_size, void* d_ws, size_t ws_size,
                              hipStream_t stream) {
    const float* drug = (const float*)d_in[0];   // (B,D,LD)
    const float* prot = (const float*)d_in[1];   // (B,D,LP)
    const float* Wd = (const float*)d_in[2];
    const float* bd = (const float*)d_in[3];
    const float* Wp = (const float*)d_in[4];
    const float* bp = (const float*)d_in[5];
    const float* Wa = (const float*)d_in[6];
    const float* ba = (const float*)d_in[7];
    const float* W1 = (const float*)d_in[8];
    const float* b1 = (const float*)d_in[9];
    const float* W2 = (const float*)d_in[10];
    const float* b2 = (const float*)d_in[11];
    const float* W3 = (const float*)d_in[12];
    const float* b3 = (const float*)d_in[13];
    const float* Wo = (const float*)d_in[14];
    const float* bo = (const float*)d_in[15];
    float* out = (float*)d_out;

    float* ws = (float*)d_ws;
    const size_t n_datt = (size_t)BB * LLD * DD;   // 196608
    const size_t n_patt = (size_t)BB * LLP * DD;   // 1572864
    float* d_att = ws;                       // reused for catt_t (B,D,LD)
    float* p_att = d_att + n_datt;           // reused for psig_t (B,D,LP)
    float* Hd    = p_att + n_patt;
    float* Hp    = Hd + n_datt;
    float* pair  = Hp + n_patt;              // B*2D = 3072
    float* h1    = pair + (size_t)BB * 2 * DD;
    float* h2    = h1 + (size_t)BB * FC1;
    float* h3    = h2 + (size_t)BB * FC2;

    // 1) projections (tiled, coalesced)
    att_proj_tiled<<<BB * (LLD / LT), DD, 0, stream>>>(drug, Wd, bd, d_att, LLD);
    att_proj_tiled<<<BB * (LLP / LT), DD, 0, stream>>>(prot, Wp, bp, p_att, LLP);

    // 2) cross means
    cross_mean_d_kernel<<<BB * LLD, DD, 0, stream>>>(d_att, p_att, Hd);
    cross_mean_p_kernel<<<BB * LLP, DD, 0, stream>>>(d_att, p_att, Hp);

    // 3) attention gemms + sigmoid, writing transposed (B,D,L) layouts
    float* catt_t = d_att;
    float* psig_t = p_att;
    att_gemm_sig_tiled<<<BB * (LLD / LT), DD, 0, stream>>>(Hd, Wa, ba, catt_t, LLD);
    att_gemm_sig_tiled<<<BB * (LLP / LT), DD, 0, stream>>>(Hp, Wa, ba, psig_t, LLP);

    // 4) gated residual + maxpool -> pair (B, 2D); wave per (b,d)
    pool_pair_kernel<<<BB * DD, 64, 0, stream>>>(drug, prot, catt_t, psig_t, pair);

    // 5) MLP — wave per output element
    fc_wave_kernel<<<(BB * FC1 * 64) / 256, 256, 0, stream>>>(pair, W1, b1, h1, 2 * DD, FC1, 1);
    fc_wave_kernel<<<(BB * FC2 * 64) / 256, 256, 0, stream>>>(h1, W2, b2, h2, FC1, FC2, 1);
    fc_wave_kernel<<<(BB * FC3 * 64) / 256, 256, 0, stream>>>(h2, W3, b3, h3, FC2, FC3, 1);
    fc_wave_kernel<<<(BB * NCLS * 64 + 255) / 256, 256, 0, stream>>>(h3, Wo, bo, out, FC3, NCLS, 0);
}

// Round 5
// 162.046 us; speedup vs baseline: 4.2169x; 1.1755x over previous
//
#include <hip/hip_runtime.h>
#include <hip/hip_bf16.h>
#include <math.h>

#define BB 8
#define DD 192
#define LLD 128
#define LLP 1024
#define FC1 1024
#define FC2 1024
#define FC3 512
#define NCLS 2
#define LT 16      // l-tile for tiled GEMM kernels
#define LTILE 16   // cross kernel l-tile
#define PTILE 128  // cross kernel p-tile
#define NLT (LLD / LTILE)  // 8  -> Hp partial slabs
#define NPT (LLP / PTILE)  // 8  -> Hd partial slabs

// ---------------------------------------------------------------------------
// Fused projections: y[b*L+l, e] = sum_d x[b,d,l]*W[e,d] + bias[e]
// blocks 0..63 = drug (L=128), 64..575 = protein (L=1024). 192 threads.
// ---------------------------------------------------------------------------
__global__ void proj_both_kernel(const float* __restrict__ drug,
                                 const float* __restrict__ prot,
                                 const float* __restrict__ Wd,
                                 const float* __restrict__ bdv,
                                 const float* __restrict__ Wp,
                                 const float* __restrict__ bpv,
                                 float* __restrict__ d_att,
                                 float* __restrict__ p_att) {
    int blk = blockIdx.x;
    const float *x, *W, *bias;
    float* y;
    int L, b, l0;
    if (blk < BB * (LLD / LT)) {            // 64 drug tiles
        x = drug; W = Wd; bias = bdv; y = d_att; L = LLD;
        b = blk >> 3; l0 = (blk & 7) * LT;
    } else {                                 // 512 protein tiles
        int idx = blk - BB * (LLD / LT);
        x = prot; W = Wp; bias = bpv; y = p_att; L = LLP;
        b = idx >> 6; l0 = (idx & 63) * LT;
    }
    int tid = threadIdx.x;  // 0..191

    __shared__ float xs[LT][DD + 4];   // xs[j][d] = x[b,d,l0+j]

    const float* xbase = x + (size_t)b * DD * L + l0;
#pragma unroll
    for (int k = 0; k < LT; ++k) {
        int idx = tid + k * DD;        // covers DD*LT = 3072
        int d = idx >> 4;
        int j = idx & (LT - 1);
        xs[j][d] = xbase[(size_t)d * L + j];
    }
    __syncthreads();

    const int e = tid;
    const float be = bias[e];
    float acc[LT];
#pragma unroll
    for (int j = 0; j < LT; ++j) acc[j] = be;

    const float4* Wr4 = (const float4*)(W + (size_t)e * DD);
#pragma unroll 2
    for (int d4 = 0; d4 < DD / 4; ++d4) {
        float4 w = Wr4[d4];
#pragma unroll
        for (int j = 0; j < LT; ++j) {
            float4 h = *(const float4*)&xs[j][d4 * 4];
            acc[j] = fmaf(h.x, w.x, acc[j]);
            acc[j] = fmaf(h.y, w.y, acc[j]);
            acc[j] = fmaf(h.z, w.z, acc[j]);
            acc[j] = fmaf(h.w, w.w, acc[j]);
        }
    }

    float* ybase = y + ((size_t)b * L + l0) * DD;
#pragma unroll
    for (int j = 0; j < LT; ++j)
        ybase[(size_t)j * DD + e] = acc[j];
}

// ---------------------------------------------------------------------------
// Fused cross-mean: computes relu(d_att[b,l,d]+p_att[b,p,d]) ONCE per element,
// accumulating partial sums for both Hd (over p) and Hp (over l).
// grid = B*NLT*NPT = 512 blocks, 192 threads (thread = d).
// Hd_part[pt][ (b*LLD+l)*DD + d ]  (raw sums over PTILE p's)
// Hp_part[lt][ (b*LLP+p)*DD + d ]  (raw sums over LTILE l's)
// ---------------------------------------------------------------------------
__global__ void cross_fused_kernel(const float* __restrict__ da,
                                   const float* __restrict__ pa,
                                   float* __restrict__ Hd_part,
                                   float* __restrict__ Hp_part) {
    int blk = blockIdx.x;
    int b = blk / (NLT * NPT);
    int r = blk - b * NLT * NPT;
    int lt = r / NPT;
    int pt = r - lt * NPT;
    int d = threadIdx.x;
    int l0 = lt * LTILE, p0 = pt * PTILE;

    const float* dab = da + ((size_t)b * LLD + l0) * DD + d;
    float a[LTILE];
#pragma unroll
    for (int i = 0; i < LTILE; ++i) a[i] = dab[(size_t)i * DD];
    float hd[LTILE];
#pragma unroll
    for (int i = 0; i < LTILE; ++i) hd[i] = 0.f;

    const float* pab = pa + ((size_t)b * LLP + p0) * DD + d;
    float* hpp = Hp_part + (size_t)lt * (BB * LLP * DD)
               + ((size_t)b * LLP + p0) * DD + d;
    for (int p = 0; p < PTILE; ++p) {
        float xp = pab[(size_t)p * DD];
        float sp = 0.f;
#pragma unroll
        for (int i = 0; i < LTILE; ++i) {
            float rv = fmaxf(a[i] + xp, 0.f);
            hd[i] += rv;
            sp += rv;
        }
        hpp[(size_t)p * DD] = sp;
    }

    float* hdp = Hd_part + (size_t)pt * (BB * LLD * DD)
               + ((size_t)b * LLD + l0) * DD + d;
#pragma unroll
    for (int i = 0; i < LTILE; ++i) hdp[(size_t)i * DD] = hd[i];
}

// ---------------------------------------------------------------------------
// Fused sigmoid-GEMM over partial-summed H, transposed coalesced output.
// blocks 0..63 = drug (sum Hd_part/LLP), 64..575 = protein (sum Hp_part/LLD).
// out written to (B,D,L) layout.
// ---------------------------------------------------------------------------
__global__ void gemm_sig_both_kernel(const float* __restrict__ Hd_part,
                                     const float* __restrict__ Hp_part,
                                     const float* __restrict__ Wa,
                                     const float* __restrict__ ba,
                                     float* __restrict__ catt_t,
                                     float* __restrict__ psig_t) {
    int blk = blockIdx.x;
    const float* Hpart;
    float* out_t;
    int L, b, l0;
    float scale;
    size_t pstride;
    if (blk < BB * (LLD / LT)) {
        b = blk >> 3; l0 = (blk & 7) * LT;
        Hpart = Hd_part; out_t = catt_t; L = LLD;
        scale = 1.0f / LLP; pstride = (size_t)BB * LLD * DD;
    } else {
        int idx = blk - BB * (LLD / LT);
        b = idx >> 6; l0 = (idx & 63) * LT;
        Hpart = Hp_part; out_t = psig_t; L = LLP;
        scale = 1.0f / LLD; pstride = (size_t)BB * LLP * DD;
    }
    int tid = threadIdx.x;

    __shared__ float hs[LT][DD];
    __shared__ float cs[LT][DD + 1];

    const float* Hbase = Hpart + ((size_t)b * L + l0) * DD;
#pragma unroll
    for (int j = 0; j < LT; ++j) {
        size_t off = (size_t)j * DD + tid;
        float s0 = 0.f, s1 = 0.f, s2 = 0.f, s3 = 0.f;
        s0 = Hbase[0 * pstride + off];
        s1 = Hbase[1 * pstride + off];
        s2 = Hbase[2 * pstride + off];
        s3 = Hbase[3 * pstride + off];
        s0 += Hbase[4 * pstride + off];
        s1 += Hbase[5 * pstride + off];
        s2 += Hbase[6 * pstride + off];
        s3 += Hbase[7 * pstride + off];
        hs[j][tid] = ((s0 + s1) + (s2 + s3)) * scale;
    }
    __syncthreads();

    const int e = tid;
    const float bias = ba[e];
    float acc[LT];
#pragma unroll
    for (int j = 0; j < LT; ++j) acc[j] = bias;

    const float4* Wr4 = (const float4*)(Wa + (size_t)e * DD);
#pragma unroll 2
    for (int d4 = 0; d4 < DD / 4; ++d4) {
        float4 w = Wr4[d4];
#pragma unroll
        for (int j = 0; j < LT; ++j) {
            float4 h = *(const float4*)&hs[j][d4 * 4];
            acc[j] = fmaf(h.x, w.x, acc[j]);
            acc[j] = fmaf(h.y, w.y, acc[j]);
            acc[j] = fmaf(h.z, w.z, acc[j]);
            acc[j] = fmaf(h.w, w.w, acc[j]);
        }
    }

#pragma unroll
    for (int j = 0; j < LT; ++j)
        cs[j][e] = 1.0f / (1.0f + __expf(-acc[j]));
    __syncthreads();

    float* obase = out_t + (size_t)b * DD * L + l0;
    for (int idx = tid; idx < LT * DD; idx += DD) {
        int eo = idx >> 4;
        int j = idx & (LT - 1);
        obase[(size_t)eo * L + j] = cs[j][eo];
    }
}

// ---------------------------------------------------------------------------
// One wave per (b,d). Coalesced contiguous reads; shfl butterfly max-reduce.
// ---------------------------------------------------------------------------
__global__ void pool_pair_kernel(const float* __restrict__ drug,
                                 const float* __restrict__ prot,
                                 const float* __restrict__ catt_t,
                                 const float* __restrict__ psig_t,
                                 float* __restrict__ pair) {
    int bd = blockIdx.x;           // b*DD + d
    int b = bd / DD;
    int d = bd - b * DD;
    int lane = threadIdx.x;        // 0..63

    const float* dr = drug + (size_t)bd * LLD;
    const float* ca = catt_t + (size_t)bd * LLD;
    float m1 = -INFINITY;
#pragma unroll
    for (int k = 0; k < LLD / 64; ++k) {
        int l = lane + 64 * k;
        m1 = fmaxf(m1, dr[l] * (0.5f + ca[l]));
    }

    const float* pr = prot + (size_t)bd * LLP;
    const float* ps = psig_t + (size_t)bd * LLP;
    float m2 = -INFINITY;
#pragma unroll
    for (int k = 0; k < LLP / 64; ++k) {
        int p = lane + 64 * k;
        m2 = fmaxf(m2, pr[p] * (0.5f + ps[p]));
    }

#pragma unroll
    for (int off = 32; off > 0; off >>= 1) {
        m1 = fmaxf(m1, __shfl_xor(m1, off));
        m2 = fmaxf(m2, __shfl_xor(m2, off));
    }
    if (lane == 0) {
        pair[b * 2 * DD + d] = m1;
        pair[b * 2 * DD + DD + d] = m2;
    }
}

// One 64-lane wave per output (b,j). Lanes split K (coalesced W reads).
__global__ void fc_wave_kernel(const float* __restrict__ x,
                               const float* __restrict__ W,
                               const float* __restrict__ bias,
                               float* __restrict__ y,
                               int K, int N, int leaky) {
    int gtid = blockIdx.x * blockDim.x + threadIdx.x;
    int wid = gtid >> 6;
    int lane = gtid & 63;
    if (wid >= BB * N) return;
    int b = wid / N;
    int j = wid - b * N;
    const float* xr = x + (size_t)b * K;
    const float* Wr = W + (size_t)j * K;
    float s = 0.f;
    for (int k = lane; k < K; k += 64) s = fmaf(xr[k], Wr[k], s);
#pragma unroll
    for (int off = 32; off > 0; off >>= 1) s += __shfl_xor(s, off);
    if (lane == 0) {
        float acc = s + bias[j];
        if (leaky) acc = (acc > 0.f) ? acc : 0.01f * acc;
        y[wid] = acc;
    }
}

extern "C" void kernel_launch(void* const* d_in, const int* in_sizes, int n_in,
                              void* d_out, int out_size, void* d_ws, size_t ws_size,
                              hipStream_t stream) {
    const float* drug = (const float*)d_in[0];   // (B,D,LD)
    const float* prot = (const float*)d_in[1];   // (B,D,LP)
    const float* Wd = (const float*)d_in[2];
    const float* bd = (const float*)d_in[3];
    const float* Wp = (const float*)d_in[4];
    const float* bp = (const float*)d_in[5];
    const float* Wa = (const float*)d_in[6];
    const float* ba = (const float*)d_in[7];
    const float* W1 = (const float*)d_in[8];
    const float* b1 = (const float*)d_in[9];
    const float* W2 = (const float*)d_in[10];
    const float* b2 = (const float*)d_in[11];
    const float* W3 = (const float*)d_in[12];
    const float* b3 = (const float*)d_in[13];
    const float* Wo = (const float*)d_in[14];
    const float* bo = (const float*)d_in[15];
    float* out = (float*)d_out;

    float* ws = (float*)d_ws;
    const size_t n_datt = (size_t)BB * LLD * DD;   // 196608
    const size_t n_patt = (size_t)BB * LLP * DD;   // 1572864
    float* d_att   = ws;                           // reused as catt_t (B,D,LD)
    float* p_att   = d_att + n_datt;               // reused as psig_t (B,D,LP)
    float* Hd_part = p_att + n_patt;               // NPT * n_datt
    float* Hp_part = Hd_part + (size_t)NPT * n_datt;   // NLT * n_patt
    float* pair    = Hp_part + (size_t)NLT * n_patt;   // B*2D
    float* h1      = pair + (size_t)BB * 2 * DD;
    float* h2      = h1 + (size_t)BB * FC1;
    float* h3      = h2 + (size_t)BB * FC2;
    // total ~16M floats (~64 MB)

    // 1) both projections, one launch
    proj_both_kernel<<<BB * (LLD / LT) + BB * (LLP / LT), DD, 0, stream>>>(
        drug, prot, Wd, bd, Wp, bp, d_att, p_att);

    // 2) fused cross-mean partials (relu computed once per element)
    cross_fused_kernel<<<BB * NLT * NPT, DD, 0, stream>>>(d_att, p_att,
                                                          Hd_part, Hp_part);

    // 3) both sigmoid-GEMMs (partial-sum reduce inside), transposed output
    float* catt_t = d_att;
    float* psig_t = p_att;
    gemm_sig_both_kernel<<<BB * (LLD / LT) + BB * (LLP / LT), DD, 0, stream>>>(
        Hd_part, Hp_part, Wa, ba, catt_t, psig_t);

    // 4) gated residual + maxpool -> pair (B, 2D); wave per (b,d)
    pool_pair_kernel<<<BB * DD, 64, 0, stream>>>(drug, prot, catt_t, psig_t, pair);

    // 5) MLP — wave per output element
    fc_wave_kernel<<<(BB * FC1 * 64) / 256, 256, 0, stream>>>(pair, W1, b1, h1, 2 * DD, FC1, 1);
    fc_wave_kernel<<<(BB * FC2 * 64) / 256, 256, 0, stream>>>(h1, W2, b2, h2, FC1, FC2, 1);
    fc_wave_kernel<<<(BB * FC3 * 64) / 256, 256, 0, stream>>>(h2, W3, b3, h3, FC2, FC3, 1);
    fc_wave_kernel<<<(BB * NCLS * 64 + 255) / 256, 256, 0, stream>>>(h3, Wo, bo, out, FC3, NCLS, 0);
}

// Round 6
// 140.387 us; speedup vs baseline: 4.8675x; 1.1543x over previous
//
#include <hip/hip_runtime.h>
#include <hip/hip_bf16.h>
#include <math.h>

#define BB 8
#define DD 192
#define LLD 128
#define LLP 1024
#define FC1 1024
#define FC2 1024
#define FC3 512
#define NCLS 2
#define LT 16      // l-tile for tiled GEMM kernels
#define LTILE 16   // pass-A l-tile
#define PTILE 128  // pass-A p-tile
#define PB 16      // pass-B p-tile
#define NLT (LLD / LTILE)  // 8
#define NPT (LLP / PTILE)  // 8  -> Hd partial slabs

// ---------------------------------------------------------------------------
// Fused projections: y[b*L+l, e] = sum_d x[b,d,l]*W[e,d] + bias[e]
// blocks 0..63 = drug (L=128), 64..575 = protein (L=1024). 192 threads.
// ---------------------------------------------------------------------------
__global__ void proj_both_kernel(const float* __restrict__ drug,
                                 const float* __restrict__ prot,
                                 const float* __restrict__ Wd,
                                 const float* __restrict__ bdv,
                                 const float* __restrict__ Wp,
                                 const float* __restrict__ bpv,
                                 float* __restrict__ d_att,
                                 float* __restrict__ p_att) {
    int blk = blockIdx.x;
    const float *x, *W, *bias;
    float* y;
    int L, b, l0;
    if (blk < BB * (LLD / LT)) {            // 64 drug tiles
        x = drug; W = Wd; bias = bdv; y = d_att; L = LLD;
        b = blk >> 3; l0 = (blk & 7) * LT;
    } else {                                 // 512 protein tiles
        int idx = blk - BB * (LLD / LT);
        x = prot; W = Wp; bias = bpv; y = p_att; L = LLP;
        b = idx >> 6; l0 = (idx & 63) * LT;
    }
    int tid = threadIdx.x;  // 0..191

    __shared__ float xs[LT][DD + 4];

    const float* xbase = x + (size_t)b * DD * L + l0;
#pragma unroll
    for (int k = 0; k < LT; ++k) {
        int idx = tid + k * DD;        // covers DD*LT = 3072
        int d = idx >> 4;
        int j = idx & (LT - 1);
        xs[j][d] = xbase[(size_t)d * L + j];
    }
    __syncthreads();

    const int e = tid;
    const float be = bias[e];
    float acc[LT];
#pragma unroll
    for (int j = 0; j < LT; ++j) acc[j] = be;

    const float4* Wr4 = (const float4*)(W + (size_t)e * DD);
#pragma unroll 2
    for (int d4 = 0; d4 < DD / 4; ++d4) {
        float4 w = Wr4[d4];
#pragma unroll
        for (int j = 0; j < LT; ++j) {
            float4 h = *(const float4*)&xs[j][d4 * 4];
            acc[j] = fmaf(h.x, w.x, acc[j]);
            acc[j] = fmaf(h.y, w.y, acc[j]);
            acc[j] = fmaf(h.z, w.z, acc[j]);
            acc[j] = fmaf(h.w, w.w, acc[j]);
        }
    }

    float* ybase = y + ((size_t)b * L + l0) * DD;
#pragma unroll
    for (int j = 0; j < LT; ++j)
        ybase[(size_t)j * DD + e] = acc[j];
}

// ---------------------------------------------------------------------------
// Combined cross pass. 192 threads (thread = d).
// blocks [0, BB*NLT*NPT)           : Pass A — Hd partial sums (drug side)
// blocks [BB*NLT*NPT, +BB*LLP/PB)  : Pass B — full Hp sum + Wa-gemm + sigmoid
//                                    + transposed psig_t write, all in-block.
// ---------------------------------------------------------------------------
__global__ void cross_both_kernel(const float* __restrict__ da,
                                  const float* __restrict__ pa,
                                  const float* __restrict__ Wa,
                                  const float* __restrict__ ba,
                                  float* __restrict__ Hd_part,
                                  float* __restrict__ psig_t) {
    int blk = blockIdx.x;
    int tid = threadIdx.x;  // 0..191

    if (blk < BB * NLT * NPT) {
        // ----- Pass A: Hd partials -----
        int b = blk / (NLT * NPT);
        int r = blk - b * NLT * NPT;
        int lt = r / NPT;
        int pt = r - lt * NPT;

        const float* dab = da + ((size_t)b * LLD + lt * LTILE) * DD + tid;
        float a[LTILE];
#pragma unroll
        for (int i = 0; i < LTILE; ++i) a[i] = dab[(size_t)i * DD];
        float hd[LTILE];
#pragma unroll
        for (int i = 0; i < LTILE; ++i) hd[i] = 0.f;

        const float* pab = pa + ((size_t)b * LLP + pt * PTILE) * DD + tid;
#pragma unroll 4
        for (int p = 0; p < PTILE; ++p) {
            float xp = pab[(size_t)p * DD];
#pragma unroll
            for (int i = 0; i < LTILE; ++i)
                hd[i] += fmaxf(a[i] + xp, 0.f);
        }

        float* hdp = Hd_part + (size_t)pt * (BB * LLD * DD)
                   + ((size_t)b * LLD + lt * LTILE) * DD + tid;
#pragma unroll
        for (int i = 0; i < LTILE; ++i) hdp[(size_t)i * DD] = hd[i];
    } else {
        // ----- Pass B: protein side, fully fused -----
        int idx = blk - BB * NLT * NPT;     // 0..BB*64-1
        int b = idx >> 6;
        int p0 = (idx & 63) * PB;

        const float* pab = pa + ((size_t)b * LLP + p0) * DD + tid;
        float xp[PB];
#pragma unroll
        for (int j = 0; j < PB; ++j) xp[j] = pab[(size_t)j * DD];
        float sp[PB];
#pragma unroll
        for (int j = 0; j < PB; ++j) sp[j] = 0.f;

        const float* dab = da + (size_t)b * LLD * DD + tid;
#pragma unroll 4
        for (int l = 0; l < LLD; ++l) {
            float al = dab[(size_t)l * DD];
#pragma unroll
            for (int j = 0; j < PB; ++j)
                sp[j] += fmaxf(al + xp[j], 0.f);
        }

        __shared__ float hs[PB][DD];
        __shared__ float cs[PB][DD + 1];
#pragma unroll
        for (int j = 0; j < PB; ++j) hs[j][tid] = sp[j] * (1.0f / LLD);
        __syncthreads();

        const int e = tid;
        const float bias = ba[e];
        float acc[PB];
#pragma unroll
        for (int j = 0; j < PB; ++j) acc[j] = bias;

        const float4* Wr4 = (const float4*)(Wa + (size_t)e * DD);
#pragma unroll 2
        for (int d4 = 0; d4 < DD / 4; ++d4) {
            float4 w = Wr4[d4];
#pragma unroll
            for (int j = 0; j < PB; ++j) {
                float4 h = *(const float4*)&hs[j][d4 * 4];
                acc[j] = fmaf(h.x, w.x, acc[j]);
                acc[j] = fmaf(h.y, w.y, acc[j]);
                acc[j] = fmaf(h.z, w.z, acc[j]);
                acc[j] = fmaf(h.w, w.w, acc[j]);
            }
        }

#pragma unroll
        for (int j = 0; j < PB; ++j)
            cs[j][e] = 1.0f / (1.0f + __expf(-acc[j]));
        __syncthreads();

        float* obase = psig_t + (size_t)b * DD * LLP + p0;
        for (int k = tid; k < PB * DD; k += DD) {
            int eo = k >> 4;
            int j = k & (PB - 1);
            obase[(size_t)eo * LLP + j] = cs[j][eo];
        }
    }
}

// ---------------------------------------------------------------------------
// Drug-side sigmoid-GEMM over Hd partials, transposed coalesced output.
// grid = BB * (LLD/LT) = 64 blocks, 192 threads.
// ---------------------------------------------------------------------------
__global__ void gemm_sig_drug_kernel(const float* __restrict__ Hd_part,
                                     const float* __restrict__ Wa,
                                     const float* __restrict__ ba,
                                     float* __restrict__ catt_t) {
    int blk = blockIdx.x;
    int b = blk >> 3;
    int l0 = (blk & 7) * LT;
    int tid = threadIdx.x;
    const size_t pstride = (size_t)BB * LLD * DD;

    __shared__ float hs[LT][DD];
    __shared__ float cs[LT][DD + 1];

    const float* Hbase = Hd_part + ((size_t)b * LLD + l0) * DD;
#pragma unroll
    for (int j = 0; j < LT; ++j) {
        size_t off = (size_t)j * DD + tid;
        float s0 = Hbase[0 * pstride + off];
        float s1 = Hbase[1 * pstride + off];
        float s2 = Hbase[2 * pstride + off];
        float s3 = Hbase[3 * pstride + off];
        s0 += Hbase[4 * pstride + off];
        s1 += Hbase[5 * pstride + off];
        s2 += Hbase[6 * pstride + off];
        s3 += Hbase[7 * pstride + off];
        hs[j][tid] = ((s0 + s1) + (s2 + s3)) * (1.0f / LLP);
    }
    __syncthreads();

    const int e = tid;
    const float bias = ba[e];
    float acc[LT];
#pragma unroll
    for (int j = 0; j < LT; ++j) acc[j] = bias;

    const float4* Wr4 = (const float4*)(Wa + (size_t)e * DD);
#pragma unroll 2
    for (int d4 = 0; d4 < DD / 4; ++d4) {
        float4 w = Wr4[d4];
#pragma unroll
        for (int j = 0; j < LT; ++j) {
            float4 h = *(const float4*)&hs[j][d4 * 4];
            acc[j] = fmaf(h.x, w.x, acc[j]);
            acc[j] = fmaf(h.y, w.y, acc[j]);
            acc[j] = fmaf(h.z, w.z, acc[j]);
            acc[j] = fmaf(h.w, w.w, acc[j]);
        }
    }

#pragma unroll
    for (int j = 0; j < LT; ++j)
        cs[j][e] = 1.0f / (1.0f + __expf(-acc[j]));
    __syncthreads();

    float* obase = catt_t + (size_t)b * DD * LLD + l0;
    for (int k = tid; k < LT * DD; k += DD) {
        int eo = k >> 4;
        int j = k & (LT - 1);
        obase[(size_t)eo * LLD + j] = cs[j][eo];
    }
}

// ---------------------------------------------------------------------------
// One wave per (b,d). Coalesced contiguous reads; shfl butterfly max-reduce.
// ---------------------------------------------------------------------------
__global__ void pool_pair_kernel(const float* __restrict__ drug,
                                 const float* __restrict__ prot,
                                 const float* __restrict__ catt_t,
                                 const float* __restrict__ psig_t,
                                 float* __restrict__ pair) {
    int bd = blockIdx.x;           // b*DD + d
    int b = bd / DD;
    int d = bd - b * DD;
    int lane = threadIdx.x;        // 0..63

    const float* dr = drug + (size_t)bd * LLD;
    const float* ca = catt_t + (size_t)bd * LLD;
    float m1 = -INFINITY;
#pragma unroll
    for (int k = 0; k < LLD / 64; ++k) {
        int l = lane + 64 * k;
        m1 = fmaxf(m1, dr[l] * (0.5f + ca[l]));
    }

    const float* pr = prot + (size_t)bd * LLP;
    const float* ps = psig_t + (size_t)bd * LLP;
    float m2 = -INFINITY;
#pragma unroll
    for (int k = 0; k < LLP / 64; ++k) {
        int p = lane + 64 * k;
        m2 = fmaxf(m2, pr[p] * (0.5f + ps[p]));
    }

#pragma unroll
    for (int off = 32; off > 0; off >>= 1) {
        m1 = fmaxf(m1, __shfl_xor(m1, off));
        m2 = fmaxf(m2, __shfl_xor(m2, off));
    }
    if (lane == 0) {
        pair[b * 2 * DD + d] = m1;
        pair[b * 2 * DD + DD + d] = m2;
    }
}

// One 64-lane wave per output (b,j). Lanes split K (coalesced W reads).
__global__ void fc_wave_kernel(const float* __restrict__ x,
                               const float* __restrict__ W,
                               const float* __restrict__ bias,
                               float* __restrict__ y,
                               int K, int N, int leaky) {
    int gtid = blockIdx.x * blockDim.x + threadIdx.x;
    int wid = gtid >> 6;
    int lane = gtid & 63;
    if (wid >= BB * N) return;
    int b = wid / N;
    int j = wid - b * N;
    const float* xr = x + (size_t)b * K;
    const float* Wr = W + (size_t)j * K;
    float s = 0.f;
    for (int k = lane; k < K; k += 64) s = fmaf(xr[k], Wr[k], s);
#pragma unroll
    for (int off = 32; off > 0; off >>= 1) s += __shfl_xor(s, off);
    if (lane == 0) {
        float acc = s + bias[j];
        if (leaky) acc = (acc > 0.f) ? acc : 0.01f * acc;
        y[wid] = acc;
    }
}

extern "C" void kernel_launch(void* const* d_in, const int* in_sizes, int n_in,
                              void* d_out, int out_size, void* d_ws, size_t ws_size,
                              hipStream_t stream) {
    const float* drug = (const float*)d_in[0];   // (B,D,LD)
    const float* prot = (const float*)d_in[1];   // (B,D,LP)
    const float* Wd = (const float*)d_in[2];
    const float* bd = (const float*)d_in[3];
    const float* Wp = (const float*)d_in[4];
    const float* bp = (const float*)d_in[5];
    const float* Wa = (const float*)d_in[6];
    const float* ba = (const float*)d_in[7];
    const float* W1 = (const float*)d_in[8];
    const float* b1 = (const float*)d_in[9];
    const float* W2 = (const float*)d_in[10];
    const float* b2 = (const float*)d_in[11];
    const float* W3 = (const float*)d_in[12];
    const float* b3 = (const float*)d_in[13];
    const float* Wo = (const float*)d_in[14];
    const float* bo = (const float*)d_in[15];
    float* out = (float*)d_out;

    float* ws = (float*)d_ws;
    const size_t n_datt = (size_t)BB * LLD * DD;   // 196608
    const size_t n_patt = (size_t)BB * LLP * DD;   // 1572864
    float* d_att   = ws;
    float* p_att   = d_att + n_datt;
    float* Hd_part = p_att + n_patt;                    // NPT * n_datt
    float* catt_t  = Hd_part + (size_t)NPT * n_datt;    // (B,D,LLD)
    float* psig_t  = catt_t + n_datt;                   // (B,D,LLP)
    float* pair    = psig_t + n_patt;                   // B*2D
    float* h1      = pair + (size_t)BB * 2 * DD;
    float* h2      = h1 + (size_t)BB * FC1;
    float* h3      = h2 + (size_t)BB * FC2;
    // total ~5.3M floats (~21 MB)

    // 1) both projections, one launch
    proj_both_kernel<<<BB * (LLD / LT) + BB * (LLP / LT), DD, 0, stream>>>(
        drug, prot, Wd, bd, Wp, bp, d_att, p_att);

    // 2) combined cross pass: A = Hd partials, B = fused protein side
    cross_both_kernel<<<BB * NLT * NPT + BB * (LLP / PB), DD, 0, stream>>>(
        d_att, p_att, Wa, ba, Hd_part, psig_t);

    // 3) drug-side sigmoid-GEMM (reduce 8 partial slabs), transposed output
    gemm_sig_drug_kernel<<<BB * (LLD / LT), DD, 0, stream>>>(Hd_part, Wa, ba, catt_t);

    // 4) gated residual + maxpool -> pair (B, 2D); wave per (b,d)
    pool_pair_kernel<<<BB * DD, 64, 0, stream>>>(drug, prot, catt_t, psig_t, pair);

    // 5) MLP — wave per output element
    fc_wave_kernel<<<(BB * FC1 * 64) / 256, 256, 0, stream>>>(pair, W1, b1, h1, 2 * DD, FC1, 1);
    fc_wave_kernel<<<(BB * FC2 * 64) / 256, 256, 0, stream>>>(h1, W2, b2, h2, FC1, FC2, 1);
    fc_wave_kernel<<<(BB * FC3 * 64) / 256, 256, 0, stream>>>(h2, W3, b3, h3, FC2, FC3, 1);
    fc_wave_kernel<<<(BB * NCLS * 64 + 255) / 256, 256, 0, stream>>>(h3, Wo, bo, out, FC3, NCLS, 0);
}

// Round 7
// 123.436 us; speedup vs baseline: 5.5359x; 1.1373x over previous
//
#include <hip/hip_runtime.h>
#include <hip/hip_bf16.h>
#include <math.h>

#define BB 8
#define DD 192
#define LLD 128
#define LLP 1024
#define FC1 1024
#define FC2 1024
#define FC3 512
#define NCLS 2
#define LT 16      // l-tile for tiled GEMM kernels
#define LTILE 16   // pass-A l-tile
#define PTILE 64   // pass-A p-tile
#define PB 8       // pass-B p-tile
#define NLT (LLD / LTILE)  // 8
#define NPT (LLP / PTILE)  // 16 -> Hd partial slabs

// ---------------------------------------------------------------------------
// Fused projections: y[b*L+l, e] = sum_d x[b,d,l]*W[e,d] + bias[e]
// blocks 0..63 = drug (L=128), 64..575 = protein (L=1024). 192 threads.
// ---------------------------------------------------------------------------
__global__ void proj_both_kernel(const float* __restrict__ drug,
                                 const float* __restrict__ prot,
                                 const float* __restrict__ Wd,
                                 const float* __restrict__ bdv,
                                 const float* __restrict__ Wp,
                                 const float* __restrict__ bpv,
                                 float* __restrict__ d_att,
                                 float* __restrict__ p_att) {
    int blk = blockIdx.x;
    const float *x, *W, *bias;
    float* y;
    int L, b, l0;
    if (blk < BB * (LLD / LT)) {            // 64 drug tiles
        x = drug; W = Wd; bias = bdv; y = d_att; L = LLD;
        b = blk >> 3; l0 = (blk & 7) * LT;
    } else {                                 // 512 protein tiles
        int idx = blk - BB * (LLD / LT);
        x = prot; W = Wp; bias = bpv; y = p_att; L = LLP;
        b = idx >> 6; l0 = (idx & 63) * LT;
    }
    int tid = threadIdx.x;  // 0..191

    __shared__ float xs[LT][DD + 4];

    const float* xbase = x + (size_t)b * DD * L + l0;
#pragma unroll
    for (int k = 0; k < LT; ++k) {
        int idx = tid + k * DD;        // covers DD*LT = 3072
        int d = idx >> 4;
        int j = idx & (LT - 1);
        xs[j][d] = xbase[(size_t)d * L + j];
    }
    __syncthreads();

    const int e = tid;
    const float be = bias[e];
    float acc[LT];
#pragma unroll
    for (int j = 0; j < LT; ++j) acc[j] = be;

    const float4* Wr4 = (const float4*)(W + (size_t)e * DD);
#pragma unroll 2
    for (int d4 = 0; d4 < DD / 4; ++d4) {
        float4 w = Wr4[d4];
#pragma unroll
        for (int j = 0; j < LT; ++j) {
            float4 h = *(const float4*)&xs[j][d4 * 4];
            acc[j] = fmaf(h.x, w.x, acc[j]);
            acc[j] = fmaf(h.y, w.y, acc[j]);
            acc[j] = fmaf(h.z, w.z, acc[j]);
            acc[j] = fmaf(h.w, w.w, acc[j]);
        }
    }

    float* ybase = y + ((size_t)b * L + l0) * DD;
#pragma unroll
    for (int j = 0; j < LT; ++j)
        ybase[(size_t)j * DD + e] = acc[j];
}

// ---------------------------------------------------------------------------
// Combined cross pass. 192 threads (thread = d).
// blocks [0, BB*NLT*NPT=1024)        : Pass A — Hd partial sums (drug side)
// blocks [1024, 1024 + BB*LLP/PB)    : Pass B — full Hp sum + Wa-gemm +
//                                      sigmoid + transposed psig_t write.
// ---------------------------------------------------------------------------
__global__ void cross_both_kernel(const float* __restrict__ da,
                                  const float* __restrict__ pa,
                                  const float* __restrict__ Wa,
                                  const float* __restrict__ ba,
                                  float* __restrict__ Hd_part,
                                  float* __restrict__ psig_t) {
    int blk = blockIdx.x;
    int tid = threadIdx.x;  // 0..191

    if (blk < BB * NLT * NPT) {
        // ----- Pass A: Hd partials over p-chunks of PTILE -----
        int b = blk / (NLT * NPT);
        int r = blk - b * NLT * NPT;
        int lt = r / NPT;
        int pt = r - lt * NPT;

        const float* dab = da + ((size_t)b * LLD + lt * LTILE) * DD + tid;
        float a[LTILE];
#pragma unroll
        for (int i = 0; i < LTILE; ++i) a[i] = dab[(size_t)i * DD];
        float hd[LTILE];
#pragma unroll
        for (int i = 0; i < LTILE; ++i) hd[i] = 0.f;

        const float* pab = pa + ((size_t)b * LLP + pt * PTILE) * DD + tid;
#pragma unroll 4
        for (int p = 0; p < PTILE; ++p) {
            float xp = pab[(size_t)p * DD];
#pragma unroll
            for (int i = 0; i < LTILE; ++i)
                hd[i] += fmaxf(a[i] + xp, 0.f);
        }

        float* hdp = Hd_part + (size_t)pt * (BB * LLD * DD)
                   + ((size_t)b * LLD + lt * LTILE) * DD + tid;
#pragma unroll
        for (int i = 0; i < LTILE; ++i) hdp[(size_t)i * DD] = hd[i];
    } else {
        // ----- Pass B: protein side, fully fused -----
        int idx = blk - BB * NLT * NPT;     // 0..BB*128-1
        int b = idx >> 7;
        int p0 = (idx & 127) * PB;

        const float* pab = pa + ((size_t)b * LLP + p0) * DD + tid;
        float xp[PB];
#pragma unroll
        for (int j = 0; j < PB; ++j) xp[j] = pab[(size_t)j * DD];
        float sp[PB];
#pragma unroll
        for (int j = 0; j < PB; ++j) sp[j] = 0.f;

        const float* dab = da + (size_t)b * LLD * DD + tid;
#pragma unroll 4
        for (int l = 0; l < LLD; ++l) {
            float al = dab[(size_t)l * DD];
#pragma unroll
            for (int j = 0; j < PB; ++j)
                sp[j] += fmaxf(al + xp[j], 0.f);
        }

        __shared__ float hs[PB][DD];
        __shared__ float cs[PB][DD + 1];
#pragma unroll
        for (int j = 0; j < PB; ++j) hs[j][tid] = sp[j] * (1.0f / LLD);
        __syncthreads();

        const int e = tid;
        const float bias = ba[e];
        float acc[PB];
#pragma unroll
        for (int j = 0; j < PB; ++j) acc[j] = bias;

        const float4* Wr4 = (const float4*)(Wa + (size_t)e * DD);
#pragma unroll 2
        for (int d4 = 0; d4 < DD / 4; ++d4) {
            float4 w = Wr4[d4];
#pragma unroll
            for (int j = 0; j < PB; ++j) {
                float4 h = *(const float4*)&hs[j][d4 * 4];
                acc[j] = fmaf(h.x, w.x, acc[j]);
                acc[j] = fmaf(h.y, w.y, acc[j]);
                acc[j] = fmaf(h.z, w.z, acc[j]);
                acc[j] = fmaf(h.w, w.w, acc[j]);
            }
        }

#pragma unroll
        for (int j = 0; j < PB; ++j)
            cs[j][e] = 1.0f / (1.0f + __expf(-acc[j]));
        __syncthreads();

        float* obase = psig_t + (size_t)b * DD * LLP + p0;
        for (int k = tid; k < PB * DD; k += DD) {
            int eo = k >> 3;          // k / PB
            int j = k & (PB - 1);
            obase[(size_t)eo * LLP + j] = cs[j][eo];
        }
    }
}

// ---------------------------------------------------------------------------
// Drug-side sigmoid-GEMM over 16 Hd partial slabs, transposed output.
// grid = BB * (LLD/LT) = 64 blocks, 192 threads.
// ---------------------------------------------------------------------------
__global__ void gemm_sig_drug_kernel(const float* __restrict__ Hd_part,
                                     const float* __restrict__ Wa,
                                     const float* __restrict__ ba,
                                     float* __restrict__ catt_t) {
    int blk = blockIdx.x;
    int b = blk >> 3;
    int l0 = (blk & 7) * LT;
    int tid = threadIdx.x;
    const size_t pstride = (size_t)BB * LLD * DD;

    __shared__ float hs[LT][DD];
    __shared__ float cs[LT][DD + 1];

    const float* Hbase = Hd_part + ((size_t)b * LLD + l0) * DD;
#pragma unroll
    for (int j = 0; j < LT; ++j) {
        size_t off = (size_t)j * DD + tid;
        float s0 = 0.f, s1 = 0.f, s2 = 0.f, s3 = 0.f;
#pragma unroll
        for (int t = 0; t < NPT; t += 4) {
            s0 += Hbase[(t + 0) * pstride + off];
            s1 += Hbase[(t + 1) * pstride + off];
            s2 += Hbase[(t + 2) * pstride + off];
            s3 += Hbase[(t + 3) * pstride + off];
        }
        hs[j][tid] = ((s0 + s1) + (s2 + s3)) * (1.0f / LLP);
    }
    __syncthreads();

    const int e = tid;
    const float bias = ba[e];
    float acc[LT];
#pragma unroll
    for (int j = 0; j < LT; ++j) acc[j] = bias;

    const float4* Wr4 = (const float4*)(Wa + (size_t)e * DD);
#pragma unroll 2
    for (int d4 = 0; d4 < DD / 4; ++d4) {
        float4 w = Wr4[d4];
#pragma unroll
        for (int j = 0; j < LT; ++j) {
            float4 h = *(const float4*)&hs[j][d4 * 4];
            acc[j] = fmaf(h.x, w.x, acc[j]);
            acc[j] = fmaf(h.y, w.y, acc[j]);
            acc[j] = fmaf(h.z, w.z, acc[j]);
            acc[j] = fmaf(h.w, w.w, acc[j]);
        }
    }

#pragma unroll
    for (int j = 0; j < LT; ++j)
        cs[j][e] = 1.0f / (1.0f + __expf(-acc[j]));
    __syncthreads();

    float* obase = catt_t + (size_t)b * DD * LLD + l0;
    for (int k = tid; k < LT * DD; k += DD) {
        int eo = k >> 4;
        int j = k & (LT - 1);
        obase[(size_t)eo * LLD + j] = cs[j][eo];
    }
}

// ---------------------------------------------------------------------------
// One wave per (b,d). Coalesced contiguous reads; shfl butterfly max-reduce.
// ---------------------------------------------------------------------------
__global__ void pool_pair_kernel(const float* __restrict__ drug,
                                 const float* __restrict__ prot,
                                 const float* __restrict__ catt_t,
                                 const float* __restrict__ psig_t,
                                 float* __restrict__ pair) {
    int bd = blockIdx.x;           // b*DD + d
    int b = bd / DD;
    int d = bd - b * DD;
    int lane = threadIdx.x;        // 0..63

    const float* dr = drug + (size_t)bd * LLD;
    const float* ca = catt_t + (size_t)bd * LLD;
    float m1 = -INFINITY;
#pragma unroll
    for (int k = 0; k < LLD / 64; ++k) {
        int l = lane + 64 * k;
        m1 = fmaxf(m1, dr[l] * (0.5f + ca[l]));
    }

    const float* pr = prot + (size_t)bd * LLP;
    const float* ps = psig_t + (size_t)bd * LLP;
    float m2 = -INFINITY;
#pragma unroll
    for (int k = 0; k < LLP / 64; ++k) {
        int p = lane + 64 * k;
        m2 = fmaxf(m2, pr[p] * (0.5f + ps[p]));
    }

#pragma unroll
    for (int off = 32; off > 0; off >>= 1) {
        m1 = fmaxf(m1, __shfl_xor(m1, off));
        m2 = fmaxf(m2, __shfl_xor(m2, off));
    }
    if (lane == 0) {
        pair[b * 2 * DD + d] = m1;
        pair[b * 2 * DD + DD + d] = m2;
    }
}

// One 64-lane wave per output (b,j). float4 lanes split K (coalesced).
__global__ void fc_wave_kernel(const float* __restrict__ x,
                               const float* __restrict__ W,
                               const float* __restrict__ bias,
                               float* __restrict__ y,
                               int K, int N, int leaky) {
    int gtid = blockIdx.x * blockDim.x + threadIdx.x;
    int wid = gtid >> 6;
    int lane = gtid & 63;
    if (wid >= BB * N) return;
    int b = wid / N;
    int j = wid - b * N;
    const float4* xr = (const float4*)(x + (size_t)b * K);
    const float4* Wr = (const float4*)(W + (size_t)j * K);
    int K4 = K >> 2;
    float s = 0.f;
    for (int k = lane; k < K4; k += 64) {
        float4 xv = xr[k];
        float4 wv = Wr[k];
        s = fmaf(xv.x, wv.x, s);
        s = fmaf(xv.y, wv.y, s);
        s = fmaf(xv.z, wv.z, s);
        s = fmaf(xv.w, wv.w, s);
    }
#pragma unroll
    for (int off = 32; off > 0; off >>= 1) s += __shfl_xor(s, off);
    if (lane == 0) {
        float acc = s + bias[j];
        if (leaky) acc = (acc > 0.f) ? acc : 0.01f * acc;
        y[wid] = acc;
    }
}

extern "C" void kernel_launch(void* const* d_in, const int* in_sizes, int n_in,
                              void* d_out, int out_size, void* d_ws, size_t ws_size,
                              hipStream_t stream) {
    const float* drug = (const float*)d_in[0];   // (B,D,LD)
    const float* prot = (const float*)d_in[1];   // (B,D,LP)
    const float* Wd = (const float*)d_in[2];
    const float* bd = (const float*)d_in[3];
    const float* Wp = (const float*)d_in[4];
    const float* bp = (const float*)d_in[5];
    const float* Wa = (const float*)d_in[6];
    const float* ba = (const float*)d_in[7];
    const float* W1 = (const float*)d_in[8];
    const float* b1 = (const float*)d_in[9];
    const float* W2 = (const float*)d_in[10];
    const float* b2 = (const float*)d_in[11];
    const float* W3 = (const float*)d_in[12];
    const float* b3 = (const float*)d_in[13];
    const float* Wo = (const float*)d_in[14];
    const float* bo = (const float*)d_in[15];
    float* out = (float*)d_out;

    float* ws = (float*)d_ws;
    const size_t n_datt = (size_t)BB * LLD * DD;   // 196608
    const size_t n_patt = (size_t)BB * LLP * DD;   // 1572864
    float* d_att   = ws;
    float* p_att   = d_att + n_datt;
    float* Hd_part = p_att + n_patt;                    // NPT * n_datt
    float* catt_t  = Hd_part + (size_t)NPT * n_datt;    // (B,D,LLD)
    float* psig_t  = catt_t + n_datt;                   // (B,D,LLP)
    float* pair    = psig_t + n_patt;                   // B*2D
    float* h1      = pair + (size_t)BB * 2 * DD;
    float* h2      = h1 + (size_t)BB * FC1;
    float* h3      = h2 + (size_t)BB * FC2;
    // total ~6.8M floats (~27 MB)

    // 1) both projections, one launch
    proj_both_kernel<<<BB * (LLD / LT) + BB * (LLP / LT), DD, 0, stream>>>(
        drug, prot, Wd, bd, Wp, bp, d_att, p_att);

    // 2) combined cross pass: A = Hd partials (16 slabs), B = fused protein
    cross_both_kernel<<<BB * NLT * NPT + BB * (LLP / PB), DD, 0, stream>>>(
        d_att, p_att, Wa, ba, Hd_part, psig_t);

    // 3) drug-side sigmoid-GEMM (reduce 16 partial slabs), transposed output
    gemm_sig_drug_kernel<<<BB * (LLD / LT), DD, 0, stream>>>(Hd_part, Wa, ba, catt_t);

    // 4) gated residual + maxpool -> pair (B, 2D); wave per (b,d)
    pool_pair_kernel<<<BB * DD, 64, 0, stream>>>(drug, prot, catt_t, psig_t, pair);

    // 5) MLP — wave per output element
    fc_wave_kernel<<<(BB * FC1 * 64) / 256, 256, 0, stream>>>(pair, W1, b1, h1, 2 * DD, FC1, 1);
    fc_wave_kernel<<<(BB * FC2 * 64) / 256, 256, 0, stream>>>(h1, W2, b2, h2, FC1, FC2, 1);
    fc_wave_kernel<<<(BB * FC3 * 64) / 256, 256, 0, stream>>>(h2, W3, b3, h3, FC2, FC3, 1);
    fc_wave_kernel<<<(BB * NCLS * 64 + 255) / 256, 256, 0, stream>>>(h3, Wo, bo, out, FC3, NCLS, 0);
}

// Round 9
// 117.190 us; speedup vs baseline: 5.8310x; 1.0533x over previous
//
#include <hip/hip_runtime.h>
#include <math.h>

typedef _Float16 hv2 __attribute__((ext_vector_type(2)));

#define BB 8
#define DD 192
#define DD2 (DD / 2)   // 96 half2 per row
#define LLD 128
#define LLP 1024
#define FC1 1024
#define FC2 1024
#define FC3 512
#define NCLS 2
#define LT 16      // l-tile for tiled GEMM kernels
#define LTILE 16   // pass-A l-tile
#define PTILE 64   // pass-A p-tile
#define PB 8       // pass-B p-tile
#define NLT (LLD / LTILE)  // 8
#define NPT (LLP / PTILE)  // 16 -> Hd partial slabs

// ---------------------------------------------------------------------------
// Fused projections: y[b*L+l, e] = sum_d x[b,d,l]*W[e,d] + bias[e]
// f32 compute, f16 output (consumed only by the cross pass).
// blocks 0..63 = drug (L=128), 64..575 = protein (L=1024). 192 threads.
// ---------------------------------------------------------------------------
__global__ void proj_both_kernel(const float* __restrict__ drug,
                                 const float* __restrict__ prot,
                                 const float* __restrict__ Wd,
                                 const float* __restrict__ bdv,
                                 const float* __restrict__ Wp,
                                 const float* __restrict__ bpv,
                                 _Float16* __restrict__ d_att,
                                 _Float16* __restrict__ p_att) {
    int blk = blockIdx.x;
    const float *x, *W, *bias;
    _Float16* y;
    int L, b, l0;
    if (blk < BB * (LLD / LT)) {            // 64 drug tiles
        x = drug; W = Wd; bias = bdv; y = d_att; L = LLD;
        b = blk >> 3; l0 = (blk & 7) * LT;
    } else {                                 // 512 protein tiles
        int idx = blk - BB * (LLD / LT);
        x = prot; W = Wp; bias = bpv; y = p_att; L = LLP;
        b = idx >> 6; l0 = (idx & 63) * LT;
    }
    int tid = threadIdx.x;  // 0..191

    __shared__ float xs[LT][DD + 4];

    const float* xbase = x + (size_t)b * DD * L + l0;
#pragma unroll
    for (int k = 0; k < LT; ++k) {
        int idx = tid + k * DD;        // covers DD*LT = 3072
        int d = idx >> 4;
        int j = idx & (LT - 1);
        xs[j][d] = xbase[(size_t)d * L + j];
    }
    __syncthreads();

    const int e = tid;
    const float be = bias[e];
    float acc[LT];
#pragma unroll
    for (int j = 0; j < LT; ++j) acc[j] = be;

    const float4* Wr4 = (const float4*)(W + (size_t)e * DD);
#pragma unroll 2
    for (int d4 = 0; d4 < DD / 4; ++d4) {
        float4 w = Wr4[d4];
#pragma unroll
        for (int j = 0; j < LT; ++j) {
            float4 h = *(const float4*)&xs[j][d4 * 4];
            acc[j] = fmaf(h.x, w.x, acc[j]);
            acc[j] = fmaf(h.y, w.y, acc[j]);
            acc[j] = fmaf(h.z, w.z, acc[j]);
            acc[j] = fmaf(h.w, w.w, acc[j]);
        }
    }

    _Float16* ybase = y + ((size_t)b * L + l0) * DD;
#pragma unroll
    for (int j = 0; j < LT; ++j)
        ybase[(size_t)j * DD + e] = (_Float16)acc[j];
}

// ---------------------------------------------------------------------------
// Combined cross pass, packed-f16 math (v_pk_add_f16 / v_pk_max_f16).
// 192 threads = 2 groups x 96 d-pairs (thread handles 2 adjacent d's).
// blocks [0, 1024)      : Pass A — Hd partial sums (f16 slabs)
// blocks [1024, 2048)   : Pass B — full Hp sum + Wa-gemm + sigmoid +
//                         transposed psig_t write (fully fused).
// ---------------------------------------------------------------------------
__global__ void cross_both_kernel(const hv2* __restrict__ da2,
                                  const hv2* __restrict__ pa2,
                                  const float* __restrict__ Wa,
                                  const float* __restrict__ ba,
                                  hv2* __restrict__ Hd_part2,
                                  float* __restrict__ psig_t) {
    int blk = blockIdx.x;
    int tid = threadIdx.x;        // 0..191
    int g = tid / DD2;            // 0 or 1
    int d2 = tid - g * DD2;       // 0..95
    hv2 z2 = {(_Float16)0, (_Float16)0};

    if (blk < BB * NLT * NPT) {
        // ----- Pass A: Hd partials over p-chunks of PTILE -----
        int b = blk / (NLT * NPT);
        int r = blk - b * NLT * NPT;
        int lt = r / NPT;
        int pt = r - lt * NPT;

        // group g covers l = lt*16 + g*8 + i, i=0..7
        const hv2* dab = da2 + ((size_t)b * LLD + lt * LTILE + g * 8) * DD2 + d2;
        hv2 a[8];
#pragma unroll
        for (int i = 0; i < 8; ++i) a[i] = dab[(size_t)i * DD2];
        hv2 hd[8];
#pragma unroll
        for (int i = 0; i < 8; ++i) hd[i] = z2;

        const hv2* pab = pa2 + ((size_t)b * LLP + pt * PTILE) * DD2 + d2;
#pragma unroll 4
        for (int p = 0; p < PTILE; ++p) {
            hv2 xp = pab[(size_t)p * DD2];
#pragma unroll
            for (int i = 0; i < 8; ++i)
                hd[i] += __builtin_elementwise_max(a[i] + xp, z2);
        }

        hv2* hdp = Hd_part2 + (size_t)pt * (BB * LLD * DD2)
                 + ((size_t)b * LLD + lt * LTILE + g * 8) * DD2 + d2;
#pragma unroll
        for (int i = 0; i < 8; ++i) hdp[(size_t)i * DD2] = hd[i];
    } else {
        // ----- Pass B: protein side, fully fused -----
        int idx = blk - BB * NLT * NPT;     // 0..BB*128-1
        int b = idx >> 7;
        int p0 = (idx & 127) * PB;
        int j0 = g * 4;                     // group g covers j = j0..j0+3

        const hv2* pab = pa2 + ((size_t)b * LLP + p0 + j0) * DD2 + d2;
        hv2 xp[4];
#pragma unroll
        for (int j = 0; j < 4; ++j) xp[j] = pab[(size_t)j * DD2];
        hv2 sp[4];
#pragma unroll
        for (int j = 0; j < 4; ++j) sp[j] = z2;

        const hv2* dab = da2 + (size_t)b * LLD * DD2 + d2;
#pragma unroll 4
        for (int l = 0; l < LLD; ++l) {
            hv2 al = dab[(size_t)l * DD2];
#pragma unroll
            for (int j = 0; j < 4; ++j)
                sp[j] += __builtin_elementwise_max(al + xp[j], z2);
        }

        __shared__ float hs[PB][DD];
        __shared__ float cs[PB][DD + 1];
#pragma unroll
        for (int j = 0; j < 4; ++j) {
            hs[j0 + j][2 * d2]     = (float)sp[j].x * (1.0f / LLD);
            hs[j0 + j][2 * d2 + 1] = (float)sp[j].y * (1.0f / LLD);
        }
        __syncthreads();

        const int e = tid;
        const float bias = ba[e];
        float acc[PB];
#pragma unroll
        for (int j = 0; j < PB; ++j) acc[j] = bias;

        const float4* Wr4 = (const float4*)(Wa + (size_t)e * DD);
#pragma unroll 2
        for (int d4 = 0; d4 < DD / 4; ++d4) {
            float4 w = Wr4[d4];
#pragma unroll
            for (int j = 0; j < PB; ++j) {
                float4 h = *(const float4*)&hs[j][d4 * 4];
                acc[j] = fmaf(h.x, w.x, acc[j]);
                acc[j] = fmaf(h.y, w.y, acc[j]);
                acc[j] = fmaf(h.z, w.z, acc[j]);
                acc[j] = fmaf(h.w, w.w, acc[j]);
            }
        }

#pragma unroll
        for (int j = 0; j < PB; ++j)
            cs[j][e] = 1.0f / (1.0f + __expf(-acc[j]));
        __syncthreads();

        float* obase = psig_t + (size_t)b * DD * LLP + p0;
        for (int k = tid; k < PB * DD; k += DD) {
            int eo = k >> 3;          // k / PB
            int j = k & (PB - 1);
            obase[(size_t)eo * LLP + j] = cs[j][eo];
        }
    }
}

// ---------------------------------------------------------------------------
// Drug-side sigmoid-GEMM over 16 f16 Hd partial slabs, transposed output.
// grid = BB * (LLD/LT) = 64 blocks, 192 threads.
// ---------------------------------------------------------------------------
__global__ void gemm_sig_drug_kernel(const hv2* __restrict__ Hd_part2,
                                     const float* __restrict__ Wa,
                                     const float* __restrict__ ba,
                                     float* __restrict__ catt_t) {
    int blk = blockIdx.x;
    int b = blk >> 3;
    int l0 = (blk & 7) * LT;
    int tid = threadIdx.x;
    int g = tid / DD2;            // 0 or 1
    int d2 = tid - g * DD2;       // 0..95
    const size_t slab2 = (size_t)BB * LLD * DD2;

    __shared__ float hs[LT][DD];
    __shared__ float cs[LT][DD + 1];

    // group g reduces rows l0+g*8 .. l0+g*8+7 over 16 slabs
    const hv2* Hb = Hd_part2 + ((size_t)b * LLD + l0 + g * 8) * DD2 + d2;
#pragma unroll
    for (int j = 0; j < 8; ++j) {
        float sx = 0.f, sy = 0.f;
#pragma unroll
        for (int t = 0; t < NPT; ++t) {
            hv2 v = Hb[(size_t)t * slab2 + (size_t)j * DD2];
            sx += (float)v.x;
            sy += (float)v.y;
        }
        hs[g * 8 + j][2 * d2]     = sx * (1.0f / LLP);
        hs[g * 8 + j][2 * d2 + 1] = sy * (1.0f / LLP);
    }
    __syncthreads();

    const int e = tid;
    const float bias = ba[e];
    float acc[LT];
#pragma unroll
    for (int j = 0; j < LT; ++j) acc[j] = bias;

    const float4* Wr4 = (const float4*)(Wa + (size_t)e * DD);
#pragma unroll 2
    for (int d4 = 0; d4 < DD / 4; ++d4) {
        float4 w = Wr4[d4];
#pragma unroll
        for (int j = 0; j < LT; ++j) {
            float4 h = *(const float4*)&hs[j][d4 * 4];
            acc[j] = fmaf(h.x, w.x, acc[j]);
            acc[j] = fmaf(h.y, w.y, acc[j]);
            acc[j] = fmaf(h.z, w.z, acc[j]);
            acc[j] = fmaf(h.w, w.w, acc[j]);
        }
    }

#pragma unroll
    for (int j = 0; j < LT; ++j)
        cs[j][e] = 1.0f / (1.0f + __expf(-acc[j]));
    __syncthreads();

    float* obase = catt_t + (size_t)b * DD * LLD + l0;
    for (int k = tid; k < LT * DD; k += DD) {
        int eo = k >> 4;
        int j = k & (LT - 1);
        obase[(size_t)eo * LLD + j] = cs[j][eo];
    }
}

// ---------------------------------------------------------------------------
// One wave per (b,d). Coalesced contiguous reads; shfl butterfly max-reduce.
// ---------------------------------------------------------------------------
__global__ void pool_pair_kernel(const float* __restrict__ drug,
                                 const float* __restrict__ prot,
                                 const float* __restrict__ catt_t,
                                 const float* __restrict__ psig_t,
                                 float* __restrict__ pair) {
    int bd = blockIdx.x;           // b*DD + d
    int b = bd / DD;
    int d = bd - b * DD;
    int lane = threadIdx.x;        // 0..63

    const float* dr = drug + (size_t)bd * LLD;
    const float* ca = catt_t + (size_t)bd * LLD;
    float m1 = -INFINITY;
#pragma unroll
    for (int k = 0; k < LLD / 64; ++k) {
        int l = lane + 64 * k;
        m1 = fmaxf(m1, dr[l] * (0.5f + ca[l]));
    }

    const float* pr = prot + (size_t)bd * LLP;
    const float* ps = psig_t + (size_t)bd * LLP;
    float m2 = -INFINITY;
#pragma unroll
    for (int k = 0; k < LLP / 64; ++k) {
        int p = lane + 64 * k;
        m2 = fmaxf(m2, pr[p] * (0.5f + ps[p]));
    }

#pragma unroll
    for (int off = 32; off > 0; off >>= 1) {
        m1 = fmaxf(m1, __shfl_xor(m1, off));
        m2 = fmaxf(m2, __shfl_xor(m2, off));
    }
    if (lane == 0) {
        pair[b * 2 * DD + d] = m1;
        pair[b * 2 * DD + DD + d] = m2;
    }
}

// One 64-lane wave per output (b,j). float4 lanes split K (coalesced).
__global__ void fc_wave_kernel(const float* __restrict__ x,
                               const float* __restrict__ W,
                               const float* __restrict__ bias,
                               float* __restrict__ y,
                               int K, int N, int leaky) {
    int gtid = blockIdx.x * blockDim.x + threadIdx.x;
    int wid = gtid >> 6;
    int lane = gtid & 63;
    if (wid >= BB * N) return;
    int b = wid / N;
    int j = wid - b * N;
    const float4* xr = (const float4*)(x + (size_t)b * K);
    const float4* Wr = (const float4*)(W + (size_t)j * K);
    int K4 = K >> 2;
    float s = 0.f;
    for (int k = lane; k < K4; k += 64) {
        float4 xv = xr[k];
        float4 wv = Wr[k];
        s = fmaf(xv.x, wv.x, s);
        s = fmaf(xv.y, wv.y, s);
        s = fmaf(xv.z, wv.z, s);
        s = fmaf(xv.w, wv.w, s);
    }
#pragma unroll
    for (int off = 32; off > 0; off >>= 1) s += __shfl_xor(s, off);
    if (lane == 0) {
        float acc = s + bias[j];
        if (leaky) acc = (acc > 0.f) ? acc : 0.01f * acc;
        y[wid] = acc;
    }
}

extern "C" void kernel_launch(void* const* d_in, const int* in_sizes, int n_in,
                              void* d_out, int out_size, void* d_ws, size_t ws_size,
                              hipStream_t stream) {
    const float* drug = (const float*)d_in[0];   // (B,D,LD)
    const float* prot = (const float*)d_in[1];   // (B,D,LP)
    const float* Wd = (const float*)d_in[2];
    const float* bd = (const float*)d_in[3];
    const float* Wp = (const float*)d_in[4];
    const float* bp = (const float*)d_in[5];
    const float* Wa = (const float*)d_in[6];
    const float* ba = (const float*)d_in[7];
    const float* W1 = (const float*)d_in[8];
    const float* b1 = (const float*)d_in[9];
    const float* W2 = (const float*)d_in[10];
    const float* b2 = (const float*)d_in[11];
    const float* W3 = (const float*)d_in[12];
    const float* b3 = (const float*)d_in[13];
    const float* Wo = (const float*)d_in[14];
    const float* bo = (const float*)d_in[15];
    float* out = (float*)d_out;

    float* ws = (float*)d_ws;
    const size_t n_datt = (size_t)BB * LLD * DD;   // 196608
    const size_t n_patt = (size_t)BB * LLP * DD;   // 1572864
    // f16 buffers (offsets in float units: halves/2)
    _Float16* d_att_h  = (_Float16*)ws;                              // n_datt halves
    _Float16* p_att_h  = (_Float16*)(ws + n_datt / 2);               // n_patt halves
    _Float16* Hd_part_h = (_Float16*)(ws + n_datt / 2 + n_patt / 2); // NPT*n_datt halves
    float* catt_t  = ws + n_datt / 2 + n_patt / 2 + (size_t)NPT * n_datt / 2;
    float* psig_t  = catt_t + n_datt;
    float* pair    = psig_t + n_patt;              // B*2D
    float* h1      = pair + (size_t)BB * 2 * DD;
    float* h2      = h1 + (size_t)BB * FC1;
    float* h3      = h2 + (size_t)BB * FC2;
    // total ~4.3M floats (~17 MB)

    // 1) both projections, one launch (f16 outputs)
    proj_both_kernel<<<BB * (LLD / LT) + BB * (LLP / LT), DD, 0, stream>>>(
        drug, prot, Wd, bd, Wp, bp, d_att_h, p_att_h);

    // 2) combined cross pass, packed-f16: A = Hd partials, B = fused protein
    cross_both_kernel<<<BB * NLT * NPT + BB * (LLP / PB), DD, 0, stream>>>(
        (const hv2*)d_att_h, (const hv2*)p_att_h, Wa, ba,
        (hv2*)Hd_part_h, psig_t);

    // 3) drug-side sigmoid-GEMM (reduce 16 f16 slabs), transposed output
    gemm_sig_drug_kernel<<<BB * (LLD / LT), DD, 0, stream>>>(
        (const hv2*)Hd_part_h, Wa, ba, catt_t);

    // 4) gated residual + maxpool -> pair (B, 2D); wave per (b,d)
    pool_pair_kernel<<<BB * DD, 64, 0, stream>>>(drug, prot, catt_t, psig_t, pair);

    // 5) MLP — wave per output element
    fc_wave_kernel<<<(BB * FC1 * 64) / 256, 256, 0, stream>>>(pair, W1, b1, h1, 2 * DD, FC1, 1);
    fc_wave_kernel<<<(BB * FC2 * 64) / 256, 256, 0, stream>>>(h1, W2, b2, h2, FC1, FC2, 1);
    fc_wave_kernel<<<(BB * FC3 * 64) / 256, 256, 0, stream>>>(h2, W3, b3, h3, FC2, FC3, 1);
    fc_wave_kernel<<<(BB * NCLS * 64 + 255) / 256, 256, 0, stream>>>(h3, Wo, bo, out, FC3, NCLS, 0);
}

// Round 10
// 110.043 us; speedup vs baseline: 6.2097x; 1.0649x over previous
//
#include <hip/hip_runtime.h>
#include <math.h>

#define BB 8
#define DD 192
#define LLD 128
#define LLP 1024
#define FC1 1024
#define FC2 1024
#define FC3 512
#define NCLS 2
#define LT 16   // l-tile for tiled GEMM kernels

// ---------------------------------------------------------------------------
// Fused projections: y[b*L+l, e] = sum_d x[b,d,l]*W[e,d] + bias[e]  (f32)
// blocks 0..63 = drug (L=128), 64..575 = protein (L=1024). 192 threads.
// ---------------------------------------------------------------------------
__global__ void proj_both_kernel(const float* __restrict__ drug,
                                 const float* __restrict__ prot,
                                 const float* __restrict__ Wd,
                                 const float* __restrict__ bdv,
                                 const float* __restrict__ Wp,
                                 const float* __restrict__ bpv,
                                 float* __restrict__ d_att,
                                 float* __restrict__ p_att) {
    int blk = blockIdx.x;
    const float *x, *W, *bias;
    float* y;
    int L, b, l0;
    if (blk < BB * (LLD / LT)) {            // 64 drug tiles
        x = drug; W = Wd; bias = bdv; y = d_att; L = LLD;
        b = blk >> 3; l0 = (blk & 7) * LT;
    } else {                                 // 512 protein tiles
        int idx = blk - BB * (LLD / LT);
        x = prot; W = Wp; bias = bpv; y = p_att; L = LLP;
        b = idx >> 6; l0 = (idx & 63) * LT;
    }
    int tid = threadIdx.x;  // 0..191

    __shared__ float xs[LT][DD + 4];

    const float* xbase = x + (size_t)b * DD * L + l0;
#pragma unroll
    for (int k = 0; k < LT; ++k) {
        int idx = tid + k * DD;        // covers DD*LT = 3072
        int d = idx >> 4;
        int j = idx & (LT - 1);
        xs[j][d] = xbase[(size_t)d * L + j];
    }
    __syncthreads();

    const int e = tid;
    const float be = bias[e];
    float acc[LT];
#pragma unroll
    for (int j = 0; j < LT; ++j) acc[j] = be;

    const float4* Wr4 = (const float4*)(W + (size_t)e * DD);
#pragma unroll 2
    for (int d4 = 0; d4 < DD / 4; ++d4) {
        float4 w = Wr4[d4];
#pragma unroll
        for (int j = 0; j < LT; ++j) {
            float4 h = *(const float4*)&xs[j][d4 * 4];
            acc[j] = fmaf(h.x, w.x, acc[j]);
            acc[j] = fmaf(h.y, w.y, acc[j]);
            acc[j] = fmaf(h.z, w.z, acc[j]);
            acc[j] = fmaf(h.w, w.w, acc[j]);
        }
    }

    float* ybase = y + ((size_t)b * L + l0) * DD;
#pragma unroll
    for (int j = 0; j < LT; ++j)
        ybase[(size_t)j * DD + e] = acc[j];
}

// ---------------------------------------------------------------------------
// Sort+prefix cross pass. One block per (b, d-pair): 8*96 = 768 blocks, 256 thr.
// For each of its 2 d-columns:
//   sort the 128 da values (bitonic, with permutation), suffix sums;
//   1024 queries q=pa[b,p,d]: k = #{sorted <= -q} (8-step search)
//     -> Hp_t[b,d,p] = ((128-k)*q + SufS[k]) / 128     (exact)
//     -> histogram (cnt,val)[k]
//   prefix-sum histogram -> Hd_t[b,d,l=perm[r]] = (s_r*CNT[r] + VAL[r]) / 1024
// ---------------------------------------------------------------------------
__global__ void cross_sort_kernel(const float* __restrict__ da,
                                  const float* __restrict__ pa,
                                  float* __restrict__ Hd_t,
                                  float* __restrict__ Hp_t) {
    int blk = blockIdx.x;            // 0..767
    int b = blk / (DD / 2);
    int dp = blk - b * (DD / 2);
    int d0 = dp * 2;
    int tid = threadIdx.x;           // 0..255

    __shared__ float skey[2][LLD];
    __shared__ int   sidx[2][LLD];
    __shared__ float sufs[2][LLD + 1];
    __shared__ int   cnt[2][LLD + 1];
    __shared__ float val[2][LLD + 1];

    // load keys + init perm
    {
        int a = tid >> 7, l = tid & 127;
        skey[a][l] = da[((size_t)b * LLD + l) * DD + d0 + a];
        sidx[a][l] = l;
    }
    // zero histograms (2 * 129 entries)
    for (int i = tid; i < 2 * (LLD + 1); i += 256) {
        int a = i / (LLD + 1), k = i - a * (LLD + 1);
        cnt[a][k] = 0;
        val[a][k] = 0.f;
    }
    __syncthreads();

    // bitonic ascending sort of both 128-element arrays
    {
        int a = tid >> 7, i = tid & 127;
        for (int k = 2; k <= LLD; k <<= 1) {
            for (int j = k >> 1; j > 0; j >>= 1) {
                int ixj = i ^ j;
                if (ixj > i) {
                    float ki = skey[a][i], kj = skey[a][ixj];
                    bool up = ((i & k) == 0);
                    if ((ki > kj) == up) {
                        skey[a][i] = kj; skey[a][ixj] = ki;
                        int t = sidx[a][i]; sidx[a][i] = sidx[a][ixj]; sidx[a][ixj] = t;
                    }
                }
                __syncthreads();
            }
        }
    }

    // suffix sums (threads 0,1 — one per array)
    if (tid < 2) {
        float s = 0.f;
        sufs[tid][LLD] = 0.f;
        for (int r = LLD - 1; r >= 0; --r) {
            s += skey[tid][r];
            sufs[tid][r] = s;
        }
    }
    __syncthreads();

    // queries: 8 batches of (128 p x 2 d)
    {
        int d_i = tid & 1, prow = tid >> 1;
        float* hprow = Hp_t + ((size_t)b * DD + d0 + d_i) * LLP;
        const float* qbase = pa + (size_t)b * LLP * DD + d0 + d_i;
#pragma unroll
        for (int batch = 0; batch < LLP / 128; ++batch) {
            int p = batch * 128 + prow;
            float q = qbase[(size_t)p * DD];
            float nq = -q;
            int pos = 0;
#pragma unroll
            for (int st = LLD; st > 0; st >>= 1) {
                int np = pos + st;
                if (np <= LLD && skey[d_i][np - 1] <= nq) pos = np;
            }
            hprow[p] = ((float)(LLD - pos) * q + sufs[d_i][pos]) * (1.0f / LLD);
            atomicAdd(&cnt[d_i][pos], 1);
            atomicAdd(&val[d_i][pos], q);
        }
    }
    __syncthreads();

    // inclusive prefix over bins 0..127 (bin 128 never activates any rank)
    if (tid < 2) {
        int c = 0; float v = 0.f;
        for (int k = 0; k < LLD; ++k) {
            c += cnt[tid][k]; cnt[tid][k] = c;
            v += val[tid][k]; val[tid][k] = v;
        }
    }
    __syncthreads();

    // finalize Hd: rank r of array a -> original row sidx[a][r]
    {
        int a = tid >> 7, r = tid & 127;
        float hv = (skey[a][r] * (float)cnt[a][r] + val[a][r]) * (1.0f / LLP);
        Hd_t[((size_t)b * DD + d0 + a) * LLD + sidx[a][r]] = hv;
    }
}

// ---------------------------------------------------------------------------
// Sigmoid-GEMM for both sides, reading transposed H (B,D,L), writing
// transposed gate (B,D,L). blocks 0..63 drug, 64..575 protein. 192 threads.
// ---------------------------------------------------------------------------
__global__ void gemm_sig_both_kernel(const float* __restrict__ Hd_t,
                                     const float* __restrict__ Hp_t,
                                     const float* __restrict__ Wa,
                                     const float* __restrict__ ba,
                                     float* __restrict__ catt_t,
                                     float* __restrict__ psig_t) {
    int blk = blockIdx.x;
    const float* Ht;
    float* out_t;
    int L, b, l0;
    if (blk < BB * (LLD / LT)) {
        b = blk >> 3; l0 = (blk & 7) * LT;
        Ht = Hd_t; out_t = catt_t; L = LLD;
    } else {
        int idx = blk - BB * (LLD / LT);
        b = idx >> 6; l0 = (idx & 63) * LT;
        Ht = Hp_t; out_t = psig_t; L = LLP;
    }
    int tid = threadIdx.x;

    __shared__ float hs[LT][DD];
    __shared__ float cs[LT][DD + 1];

    // each thread owns d-row `tid`: 16 consecutive floats (one 64B line)
    const float* hrow = Ht + ((size_t)b * DD + tid) * L + l0;
#pragma unroll
    for (int j = 0; j < LT; ++j) hs[j][tid] = hrow[j];
    __syncthreads();

    const int e = tid;
    const float bias = ba[e];
    float acc[LT];
#pragma unroll
    for (int j = 0; j < LT; ++j) acc[j] = bias;

    const float4* Wr4 = (const float4*)(Wa + (size_t)e * DD);
#pragma unroll 2
    for (int d4 = 0; d4 < DD / 4; ++d4) {
        float4 w = Wr4[d4];
#pragma unroll
        for (int j = 0; j < LT; ++j) {
            float4 h = *(const float4*)&hs[j][d4 * 4];
            acc[j] = fmaf(h.x, w.x, acc[j]);
            acc[j] = fmaf(h.y, w.y, acc[j]);
            acc[j] = fmaf(h.z, w.z, acc[j]);
            acc[j] = fmaf(h.w, w.w, acc[j]);
        }
    }

#pragma unroll
    for (int j = 0; j < LT; ++j)
        cs[j][e] = 1.0f / (1.0f + __expf(-acc[j]));
    __syncthreads();

    float* obase = out_t + (size_t)b * DD * L + l0;
    for (int k = tid; k < LT * DD; k += DD) {
        int eo = k >> 4;
        int j = k & (LT - 1);
        obase[(size_t)eo * L + j] = cs[j][eo];
    }
}

// ---------------------------------------------------------------------------
// One wave per (b,d). Coalesced contiguous reads; shfl butterfly max-reduce.
// ---------------------------------------------------------------------------
__global__ void pool_pair_kernel(const float* __restrict__ drug,
                                 const float* __restrict__ prot,
                                 const float* __restrict__ catt_t,
                                 const float* __restrict__ psig_t,
                                 float* __restrict__ pair) {
    int bd = blockIdx.x;           // b*DD + d
    int b = bd / DD;
    int d = bd - b * DD;
    int lane = threadIdx.x;        // 0..63

    const float* dr = drug + (size_t)bd * LLD;
    const float* ca = catt_t + (size_t)bd * LLD;
    float m1 = -INFINITY;
#pragma unroll
    for (int k = 0; k < LLD / 64; ++k) {
        int l = lane + 64 * k;
        m1 = fmaxf(m1, dr[l] * (0.5f + ca[l]));
    }

    const float* pr = prot + (size_t)bd * LLP;
    const float* ps = psig_t + (size_t)bd * LLP;
    float m2 = -INFINITY;
#pragma unroll
    for (int k = 0; k < LLP / 64; ++k) {
        int p = lane + 64 * k;
        m2 = fmaxf(m2, pr[p] * (0.5f + ps[p]));
    }

#pragma unroll
    for (int off = 32; off > 0; off >>= 1) {
        m1 = fmaxf(m1, __shfl_xor(m1, off));
        m2 = fmaxf(m2, __shfl_xor(m2, off));
    }
    if (lane == 0) {
        pair[b * 2 * DD + d] = m1;
        pair[b * 2 * DD + DD + d] = m2;
    }
}

// One 64-lane wave per output (b,j). float4 lanes split K (coalesced).
__global__ void fc_wave_kernel(const float* __restrict__ x,
                               const float* __restrict__ W,
                               const float* __restrict__ bias,
                               float* __restrict__ y,
                               int K, int N, int leaky) {
    int gtid = blockIdx.x * blockDim.x + threadIdx.x;
    int wid = gtid >> 6;
    int lane = gtid & 63;
    if (wid >= BB * N) return;
    int b = wid / N;
    int j = wid - b * N;
    const float4* xr = (const float4*)(x + (size_t)b * K);
    const float4* Wr = (const float4*)(W + (size_t)j * K);
    int K4 = K >> 2;
    float s = 0.f;
    for (int k = lane; k < K4; k += 64) {
        float4 xv = xr[k];
        float4 wv = Wr[k];
        s = fmaf(xv.x, wv.x, s);
        s = fmaf(xv.y, wv.y, s);
        s = fmaf(xv.z, wv.z, s);
        s = fmaf(xv.w, wv.w, s);
    }
#pragma unroll
    for (int off = 32; off > 0; off >>= 1) s += __shfl_xor(s, off);
    if (lane == 0) {
        float acc = s + bias[j];
        if (leaky) acc = (acc > 0.f) ? acc : 0.01f * acc;
        y[wid] = acc;
    }
}

extern "C" void kernel_launch(void* const* d_in, const int* in_sizes, int n_in,
                              void* d_out, int out_size, void* d_ws, size_t ws_size,
                              hipStream_t stream) {
    const float* drug = (const float*)d_in[0];   // (B,D,LD)
    const float* prot = (const float*)d_in[1];   // (B,D,LP)
    const float* Wd = (const float*)d_in[2];
    const float* bd = (const float*)d_in[3];
    const float* Wp = (const float*)d_in[4];
    const float* bp = (const float*)d_in[5];
    const float* Wa = (const float*)d_in[6];
    const float* ba = (const float*)d_in[7];
    const float* W1 = (const float*)d_in[8];
    const float* b1 = (const float*)d_in[9];
    const float* W2 = (const float*)d_in[10];
    const float* b2 = (const float*)d_in[11];
    const float* W3 = (const float*)d_in[12];
    const float* b3 = (const float*)d_in[13];
    const float* Wo = (const float*)d_in[14];
    const float* bo = (const float*)d_in[15];
    float* out = (float*)d_out;

    float* ws = (float*)d_ws;
    const size_t n_datt = (size_t)BB * LLD * DD;   // 196608
    const size_t n_patt = (size_t)BB * LLP * DD;   // 1572864
    float* d_att  = ws;                     // (B*LD, D)
    float* p_att  = d_att + n_datt;         // (B*LP, D)
    float* Hd_t   = p_att + n_patt;         // (B,D,LD)
    float* Hp_t   = Hd_t + n_datt;          // (B,D,LP)
    float* catt_t = Hp_t + n_patt;          // (B,D,LD)
    float* psig_t = catt_t + n_datt;        // (B,D,LP)
    float* pair   = psig_t + n_patt;        // B*2D
    float* h1     = pair + (size_t)BB * 2 * DD;
    float* h2     = h1 + (size_t)BB * FC1;
    float* h3     = h2 + (size_t)BB * FC2;
    // total ~5.3M floats (~21 MB)

    // 1) both projections, one launch
    proj_both_kernel<<<BB * (LLD / LT) + BB * (LLP / LT), DD, 0, stream>>>(
        drug, prot, Wd, bd, Wp, bp, d_att, p_att);

    // 2) sort+prefix cross pass (exact f32), transposed H outputs
    cross_sort_kernel<<<BB * (DD / 2), 256, 0, stream>>>(d_att, p_att, Hd_t, Hp_t);

    // 3) both sigmoid-GEMMs, transposed gates
    gemm_sig_both_kernel<<<BB * (LLD / LT) + BB * (LLP / LT), DD, 0, stream>>>(
        Hd_t, Hp_t, Wa, ba, catt_t, psig_t);

    // 4) gated residual + maxpool -> pair (B, 2D); wave per (b,d)
    pool_pair_kernel<<<BB * DD, 64, 0, stream>>>(drug, prot, catt_t, psig_t, pair);

    // 5) MLP — wave per output element
    fc_wave_kernel<<<(BB * FC1 * 64) / 256, 256, 0, stream>>>(pair, W1, b1, h1, 2 * DD, FC1, 1);
    fc_wave_kernel<<<(BB * FC2 * 64) / 256, 256, 0, stream>>>(h1, W2, b2, h2, FC1, FC2, 1);
    fc_wave_kernel<<<(BB * FC3 * 64) / 256, 256, 0, stream>>>(h2, W3, b3, h3, FC2, FC3, 1);
    fc_wave_kernel<<<(BB * NCLS * 64 + 255) / 256, 256, 0, stream>>>(h3, Wo, bo, out, FC3, NCLS, 0);
}